// Round 7
// baseline (535.212 us; speedup 1.0000x reference)
//
#include <hip/hip_runtime.h>

#define NN 50000
#define NE 1600000
#define CIN 512
#define CH 64
#define CL 32

#define SCAN_CHUNK 1024
#define NSCAN ((NN + SCAN_CHUNK - 1) / SCAN_CHUNK)  // 49

#define BKN 256                                // nodes per bucket
#define NB ((NN + BKN - 1) / BKN)              // 196 buckets
#define CHUNK 8192                             // edges per scatA block
#define NBLKA ((NE + CHUNK - 1) / CHUNK)       // 196
#define SEGCAP 12288                           // bucket segment cap (mean 8192 + 45 sigma)

typedef float f32x4 __attribute__((ext_vector_type(4)));
typedef short bf16x8 __attribute__((ext_vector_type(8)));

// ---------------- bf16 split helpers (RTNE, pure bit ops) ----------------

__device__ inline unsigned short bf_hi(float f) {
    union { float f; unsigned u; } a; a.f = f;
    unsigned r = a.u + 0x7FFFu + ((a.u >> 16) & 1u);
    return (unsigned short)(r >> 16);
}
__device__ inline float bf_to_f(unsigned short h) {
    union { unsigned u; float f; } b; b.u = ((unsigned)h) << 16; return b.f;
}
__device__ inline void split_bf16(float f, unsigned short& hi, unsigned short& lo) {
    hi = bf_hi(f);
    lo = bf_hi(f - bf_to_f(hi));
}
__device__ inline void split4(const float4& v, ushort4& h, ushort4& l) {
    split_bf16(v.x, h.x, l.x); split_bf16(v.y, h.y, l.y);
    split_bf16(v.z, h.z, l.z); split_bf16(v.w, h.w, l.w);
}
__device__ inline void split8(const float4& v0, const float4& v1, bf16x8& h, bf16x8& l) {
    ushort4 h0, l0, h1, l1;
    split4(v0, h0, l0); split4(v1, h1, l1);
    h = (bf16x8){(short)h0.x, (short)h0.y, (short)h0.z, (short)h0.w,
                 (short)h1.x, (short)h1.y, (short)h1.z, (short)h1.w};
    l = (bf16x8){(short)l0.x, (short)l0.y, (short)l0.z, (short)l0.w,
                 (short)l1.x, (short)l1.y, (short)l1.z, (short)l1.w};
}

// XOR-swizzled LDS frag read: planes are [row][64k] bf16, row stride 128B
__device__ inline bf16x8 frag(const char* plane, int row, int koff_bytes) {
    int off = (row * 128 + koff_bytes) ^ ((row & 7) << 4);
    return *(const bf16x8*)(plane + off);
}

// ---------------- weight prep: transpose + split to bf16 hi/lo ----------------

__global__ void k_prep(const float* __restrict__ W1, const float* __restrict__ Wd2,
                       unsigned short* __restrict__ wt1_hi, unsigned short* __restrict__ wt1_lo,
                       unsigned short* __restrict__ wt2_hi, unsigned short* __restrict__ wt2_lo) {
    int id = blockIdx.x * blockDim.x + threadIdx.x;  // 0..65535
    if (id < CIN * CH) {                 // W1: [512][64] -> wt1[n=64][k=512]
        int k = id >> 6, n = id & 63;
        unsigned short h, lo; split_bf16(W1[id], h, lo);
        wt1_hi[n * CIN + k] = h; wt1_lo[n * CIN + k] = lo;
    } else {                             // Wd2: [64][512] -> wt2[n=512][k=64]
        int e = id - CIN * CH;
        int k = e >> 9, n = e & 511;
        unsigned short h, lo; split_bf16(Wd2[e], h, lo);
        wt2_hi[n * CH + k] = h; wt2_lo[n * CH + k] = lo;
    }
}

// ---------------- CSR build ----------------

__global__ void k_init(int* cnt, int* gcur) {
    int i = blockIdx.x * blockDim.x + threadIdx.x;
    if (i < NN) cnt[i] = 0;
    if (i < NB) gcur[i] = 0;
}

__global__ void k_deg(const int* __restrict__ dst, int* __restrict__ cnt) {
    int e = blockIdx.x * blockDim.x + threadIdx.x;
    if (e < NE) atomicAdd(&cnt[dst[e]], 1);
}

__global__ void k_dis(const int* __restrict__ cnt, float* __restrict__ dis) {
    int i = blockIdx.x * blockDim.x + threadIdx.x;
    if (i < NN) dis[i] = rsqrtf((float)(cnt[i] + 1));  // +1 self-loop
}

__global__ void k_scan_block(const int* __restrict__ cnt, int* __restrict__ rowptr,
                             int* __restrict__ bsum) {
    __shared__ int sd[256];
    int t = threadIdx.x, b = blockIdx.x;
    int base = b * SCAN_CHUNK + t * 4;
    int c[4], s = 0;
#pragma unroll
    for (int j = 0; j < 4; j++) {
        int i = base + j;
        c[j] = (i < NN) ? cnt[i] : 0;
        s += c[j];
    }
    sd[t] = s;
    __syncthreads();
    for (int off = 1; off < 256; off <<= 1) {
        int v = (t >= off) ? sd[t - off] : 0;
        __syncthreads();
        sd[t] += v;
        __syncthreads();
    }
    int incl = sd[t];
    int run = incl - s;
#pragma unroll
    for (int j = 0; j < 4; j++) {
        int i = base + j;
        if (i < NN) rowptr[i] = run;
        run += c[j];
    }
    if (t == 255) bsum[b] = incl;
}

__global__ void k_scan_top(int* bsum, int* rowptr) {
    int run = 0;
    for (int b = 0; b < NSCAN; b++) {
        int v = bsum[b];
        bsum[b] = run;
        run += v;
    }
    rowptr[NN] = run;
}

__global__ void k_scan_add(int* rowptr, const int* __restrict__ bsum) {
    int i = blockIdx.x * blockDim.x + threadIdx.x;
    if (i < NN) rowptr[i] += bsum[i >> 10];
}

// ---- binned scatter phase A: bucket-sort edge pairs into csr segments ----
// pair u32 = (dst<<16) | src  (both < 65536). pairbuf aliases csr.

__launch_bounds__(256)
__global__ void k_scatA(const int* __restrict__ srcIdx, const int* __restrict__ dstIdx,
                        const int* __restrict__ rowptr, int* __restrict__ gcur,
                        unsigned int* __restrict__ pairbuf) {
    __shared__ unsigned int stage[CHUNK];          // 32 KB
    __shared__ unsigned char bids[CHUNK];          // 8 KB
    __shared__ int hist[256], lbase[256], runcur[256], gbase[256];
    const int t = threadIdx.x;
    const int e0 = blockIdx.x * CHUNK;
    const int tot = min(NE - e0, CHUNK);

    hist[t] = 0; runcur[t] = 0;
    __syncthreads();

    unsigned int pr[CHUNK / 256];
    unsigned char bk[CHUNK / 256];
#pragma unroll
    for (int k = 0; k < CHUNK / 256; ++k) {
        int e = e0 + k * 256 + t;
        if (e < NE) {
            int s = srcIdx[e], d = dstIdx[e];
            pr[k] = ((unsigned)d << 16) | (unsigned)s;
            bk[k] = (unsigned char)(d >> 8);
            atomicAdd(&hist[bk[k]], 1);
        }
    }
    __syncthreads();
    // exclusive scan of hist over 256 entries
    int cb = hist[t];
    lbase[t] = cb;
    __syncthreads();
    for (int off = 1; off < 256; off <<= 1) {
        int v = (t >= off) ? lbase[t - off] : 0;
        __syncthreads();
        lbase[t] += v;
        __syncthreads();
    }
    int excl = lbase[t] - cb;
    __syncthreads();
    lbase[t] = excl;
    // reserve global run per bucket
    if (t < NB) {
        int base = rowptr[t * BKN];
        gbase[t] = base + (cb ? atomicAdd(&gcur[t], cb) : 0);
    }
    __syncthreads();
    // pass 2: place into stage bucket-sorted
#pragma unroll
    for (int k = 0; k < CHUNK / 256; ++k) {
        int e = e0 + k * 256 + t;
        if (e < NE) {
            int b = bk[k];
            int off = lbase[b] + atomicAdd(&runcur[b], 1);
            stage[off] = pr[k];
            bids[off] = (unsigned char)b;
        }
    }
    __syncthreads();
    // copy out: consecutive i within a bucket -> consecutive global positions
    for (int i = t; i < tot; i += 256) {
        int b = bids[i];
        pairbuf[gbase[b] + (i - lbase[b])] = stage[i];
    }
}

// ---- binned scatter phase B: node-level ordering within bucket, in-place ----

__launch_bounds__(256)
__global__ void k_scatB(const int* __restrict__ rowptr, int* __restrict__ csr) {
    __shared__ int lcsr[SEGCAP];       // 48 KB
    __shared__ int lrp[BKN + 1];
    __shared__ int lcur[BKN];
    const int t = threadIdx.x, b = blockIdx.x;
    const int n0 = b * BKN;
    const int nn = min(BKN, NN - n0);
    for (int i = t; i <= nn; i += 256) lrp[i] = rowptr[n0 + i];
    if (t < BKN) lcur[t] = 0;
    __syncthreads();
    const int p0 = lrp[0], p1 = lrp[nn];
    const int cnt = p1 - p0;
    for (int i = p0 + t; i < p1; i += 256) {
        unsigned int pr = ((const unsigned int*)csr)[i];
        int dL = (int)(pr >> 16) - n0;
        int slot = (lrp[dL] - p0) + atomicAdd(&lcur[dL], 1);
        lcsr[slot] = (int)(pr & 0xFFFFu);
    }
    __syncthreads();
    for (int i = t; i < cnt; i += 256) csr[p0 + i] = lcsr[i];
}

// ---------------- GEMM1 (MFMA split-bf16): hw1s = (x @ W1) * dis[row] ----------------
// M=50000 (64/block), N=64, K=512 (chunks of 64)

__launch_bounds__(256)
__global__ void k_gemm1_mfma(const float* __restrict__ x,
                             const unsigned short* __restrict__ wt_hi,
                             const unsigned short* __restrict__ wt_lo,
                             const float* __restrict__ dis,
                             float* __restrict__ hw1) {
    __shared__ alignas(16) char Ahi[8192], Alo[8192], Bhi[8192], Blo[8192];
    const int t = threadIdx.x;
    const int w = t >> 6, l = t & 63;
    const int row0 = blockIdx.x * 64;
    const int r = t >> 2;            // staging row 0..63
    const int kq = (t & 3) * 16;     // staging k start (elems)

    f32x4 zero4 = {0.f, 0.f, 0.f, 0.f};
    f32x4 acc[4];
#pragma unroll
    for (int f = 0; f < 4; ++f) acc[f] = zero4;

    const bool inb = (row0 + r) < NN;

    for (int kc = 0; kc < CIN; kc += 64) {
        // stage A: x tile 64x64 fp32 -> hi/lo bf16 planes (swizzled)
        const float* xp = x + (row0 + r) * CIN + kc + kq;
#pragma unroll
        for (int j = 0; j < 4; ++j) {
            float4 v = inb ? *(const float4*)(xp + j * 4) : make_float4(0.f, 0.f, 0.f, 0.f);
            ushort4 h4, l4; split4(v, h4, l4);
            int so = (r * 128 + (kq + j * 4) * 2) ^ ((r & 7) << 4);
            *(ushort4*)(Ahi + so) = h4;
            *(ushort4*)(Alo + so) = l4;
        }
        // stage B: wt1 tile [n=64][k=64] bf16 hi/lo (swizzled)
        {
            const char* bh = (const char*)wt_hi;
            const char* bl = (const char*)wt_lo;
            int kb = (t & 3) * 32;   // byte offset within 128B chunk-row
#pragma unroll
            for (int j = 0; j < 2; ++j) {
                int srcoff = r * (CIN * 2) + kc * 2 + kb + j * 16;
                int so = (r * 128 + kb + j * 16) ^ ((r & 7) << 4);
                *(int4*)(Bhi + so) = *(const int4*)(bh + srcoff);
                *(int4*)(Blo + so) = *(const int4*)(bl + srcoff);
            }
        }
        __syncthreads();
#pragma unroll
        for (int ks = 0; ks < 2; ++ks) {
            int kb = ks * 64 + (l >> 4) * 16;
            bf16x8 aH = frag(Ahi, w * 16 + (l & 15), kb);
            bf16x8 aL = frag(Alo, w * 16 + (l & 15), kb);
#pragma unroll
            for (int f = 0; f < 4; ++f) {
                bf16x8 bH = frag(Bhi, f * 16 + (l & 15), kb);
                bf16x8 bL = frag(Blo, f * 16 + (l & 15), kb);
                acc[f] = __builtin_amdgcn_mfma_f32_16x16x32_bf16(aH, bH, acc[f], 0, 0, 0);
                acc[f] = __builtin_amdgcn_mfma_f32_16x16x32_bf16(aL, bH, acc[f], 0, 0, 0);
                acc[f] = __builtin_amdgcn_mfma_f32_16x16x32_bf16(aH, bL, acc[f], 0, 0, 0);
            }
        }
        __syncthreads();
    }
    // epilogue: C/D layout col=lane&15, row=(lane>>4)*4+reg; pre-scale by dis[row]
#pragma unroll
    for (int i = 0; i < 4; ++i) {
        int row = row0 + w * 16 + (l >> 4) * 4 + i;
        if (row < NN) {
            float di = dis[row];
#pragma unroll
            for (int f = 0; f < 4; ++f)
                hw1[row * CH + f * 16 + (l & 15)] = di * acc[f][i];
        }
    }
}

// ---------------- Aggregation 1: h = relu(dis[i]*sum(hw1s) + b1), H=64 ----------------

__launch_bounds__(256)
__global__ void k_agg1(const float* __restrict__ hw1s, const float* __restrict__ dis,
                       const int* __restrict__ rowptr, const int* __restrict__ csr,
                       const float* __restrict__ b1, float* __restrict__ h) {
    int i = blockIdx.x * 4 + (threadIdx.x >> 6);
    if (i >= NN) return;
    int c = threadIdx.x & 63;
    float a0 = hw1s[i * CH + c];  // self-loop term (pre-scaled): dis[i]*hw1[i]
    float a1 = 0.f, a2 = 0.f, a3 = 0.f, a4 = 0.f, a5 = 0.f, a6 = 0.f, a7 = 0.f;
    int p = rowptr[i], p1 = rowptr[i + 1];
    for (; p + 8 <= p1; p += 8) {
        int s0 = csr[p + 0], s1 = csr[p + 1], s2 = csr[p + 2], s3 = csr[p + 3];
        int s4 = csr[p + 4], s5 = csr[p + 5], s6 = csr[p + 6], s7 = csr[p + 7];
        a0 += hw1s[s0 * CH + c]; a1 += hw1s[s1 * CH + c];
        a2 += hw1s[s2 * CH + c]; a3 += hw1s[s3 * CH + c];
        a4 += hw1s[s4 * CH + c]; a5 += hw1s[s5 * CH + c];
        a6 += hw1s[s6 * CH + c]; a7 += hw1s[s7 * CH + c];
    }
    for (; p < p1; ++p) a0 += hw1s[csr[p] * CH + c];
    float sum = ((a0 + a1) + (a2 + a3)) + ((a4 + a5) + (a6 + a7));
    float v = dis[i] * sum + b1[c];
    h[i * CH + c] = v > 0.f ? v : 0.f;
}

// ---------------- GEMM2: hzs = (h @ W2) * dis[n]  (50000x64 @ 64x32) ----------------

__global__ void k_gemm2(const float* __restrict__ h, const float* __restrict__ W2,
                        const float* __restrict__ dis, float* __restrict__ hz) {
    int t = blockIdx.x * blockDim.x + threadIdx.x;
    int n = t >> 5, c = t & 31;
    if (n >= NN) return;
    float acc = 0.f;
#pragma unroll
    for (int k = 0; k < CH; k++) acc = fmaf(h[n * CH + k], W2[k * CL + c], acc);
    hz[n * CL + c] = acc * dis[n];
}

// ---------------- Aggregation 2: z = relu(dis[i]*sum(hzs) + b2), H=32 ----------------

__launch_bounds__(256)
__global__ void k_agg2(const float* __restrict__ hzs, const float* __restrict__ dis,
                       const int* __restrict__ rowptr, const int* __restrict__ csr,
                       const float* __restrict__ b2, float* __restrict__ z) {
    int wave = blockIdx.x * 4 + (threadIdx.x >> 6);
    int half = (threadIdx.x >> 5) & 1;
    int i = wave * 2 + half;
    if (i >= NN) return;
    int c = threadIdx.x & 31;
    float a0 = hzs[i * CL + c];
    float a1 = 0.f, a2 = 0.f, a3 = 0.f, a4 = 0.f, a5 = 0.f, a6 = 0.f, a7 = 0.f;
    int p = rowptr[i], p1 = rowptr[i + 1];
    for (; p + 8 <= p1; p += 8) {
        int s0 = csr[p + 0], s1 = csr[p + 1], s2 = csr[p + 2], s3 = csr[p + 3];
        int s4 = csr[p + 4], s5 = csr[p + 5], s6 = csr[p + 6], s7 = csr[p + 7];
        a0 += hzs[s0 * CL + c]; a1 += hzs[s1 * CL + c];
        a2 += hzs[s2 * CL + c]; a3 += hzs[s3 * CL + c];
        a4 += hzs[s4 * CL + c]; a5 += hzs[s5 * CL + c];
        a6 += hzs[s6 * CL + c]; a7 += hzs[s7 * CL + c];
    }
    for (; p < p1; ++p) a0 += hzs[csr[p] * CL + c];
    float sum = ((a0 + a1) + (a2 + a3)) + ((a4 + a5) + (a6 + a7));
    float v = dis[i] * sum + b2[c];
    z[i * CL + c] = v > 0.f ? v : 0.f;
}

// ---------------- Decoder layer 1: d = relu(z @ Wd1 + bd1) ----------------

__global__ void k_dmlp(const float* __restrict__ z, const float* __restrict__ Wd1,
                       const float* __restrict__ bd1, float* __restrict__ dout) {
    int g = blockIdx.x * blockDim.x + threadIdx.x;
    int n = g >> 6, c = g & 63;
    if (n >= NN) return;
    float acc = bd1[c];
    const float* zp = z + n * CL;
#pragma unroll
    for (int k = 0; k < CL; ++k) acc = fmaf(zp[k], Wd1[k * CH + c], acc);
    dout[n * CH + c] = acc > 0.f ? acc : 0.f;
}

// ---------------- Decoder layer 2 (MFMA split-bf16, LDS-free) + sigmoid ----------------
// M=50000 (64/block), N=512 (2 tiles of 256), K=64. A and B fragments loaded
// directly from global (d is L2-resident 12.8MB; wt2 is 128KB L2-resident).
// No LDS, no barriers -> occupancy limited only by VGPRs.

__launch_bounds__(256)
__global__ void k_dec2(const float* __restrict__ d,
                       const unsigned short* __restrict__ wt2_hi,
                       const unsigned short* __restrict__ wt2_lo,
                       const float* __restrict__ bd2,
                       float* __restrict__ out) {
    const int t = threadIdx.x;
    const int w = t >> 6, l = t & 63;
    const int mt = blockIdx.x >> 1, nt = blockIdx.x & 1;
    const int row0 = mt * 64, col0 = nt * 256;
    const int lq = l >> 4, lr = l & 15;

    // A fragments direct from global: lane holds A[m=lr][k=ks*32+lq*8 .. +8]
    const int arow = row0 + w * 16 + lr;
    const bool inb = arow < NN;
    bf16x8 aH[2], aL[2];
#pragma unroll
    for (int ks = 0; ks < 2; ++ks) {
        const float* ap = d + arow * CH + ks * 32 + lq * 8;
        float4 v0 = inb ? *(const float4*)ap : make_float4(0.f, 0.f, 0.f, 0.f);
        float4 v1 = inb ? *(const float4*)(ap + 4) : make_float4(0.f, 0.f, 0.f, 0.f);
        split8(v0, v1, aH[ks], aL[ks]);
    }

    f32x4 zero4 = {0.f, 0.f, 0.f, 0.f};
    f32x4 acc[16];
#pragma unroll
    for (int f = 0; f < 16; ++f) acc[f] = zero4;

#pragma unroll
    for (int f = 0; f < 16; ++f) {
        const int brow = col0 + f * 16 + lr;
#pragma unroll
        for (int ks = 0; ks < 2; ++ks) {
            const int boff = brow * CH + ks * 32 + lq * 8;
            bf16x8 bH = *(const bf16x8*)(wt2_hi + boff);
            bf16x8 bL = *(const bf16x8*)(wt2_lo + boff);
            acc[f] = __builtin_amdgcn_mfma_f32_16x16x32_bf16(aH[ks], bH, acc[f], 0, 0, 0);
            acc[f] = __builtin_amdgcn_mfma_f32_16x16x32_bf16(aL[ks], bH, acc[f], 0, 0, 0);
            acc[f] = __builtin_amdgcn_mfma_f32_16x16x32_bf16(aH[ks], bL, acc[f], 0, 0, 0);
        }
    }

#pragma unroll
    for (int f = 0; f < 16; ++f) {
        int c = col0 + f * 16 + lr;
        float bias = bd2[c];
#pragma unroll
        for (int i = 0; i < 4; ++i) {
            int row = row0 + w * 16 + lq * 4 + i;
            if (row < NN) {
                float v = acc[f][i] + bias;
                out[row * CIN + c] = 1.f / (1.f + __expf(-v));
            }
        }
    }
}

// ---------------- launch ----------------

extern "C" void kernel_launch(void* const* d_in, const int* in_sizes, int n_in,
                              void* d_out, int out_size, void* d_ws, size_t ws_size,
                              hipStream_t stream) {
    const float* x   = (const float*)d_in[0];
    const int*   ei  = (const int*)d_in[1];
    const float* W1  = (const float*)d_in[2];
    const float* b1  = (const float*)d_in[3];
    const float* W2  = (const float*)d_in[4];
    const float* b2  = (const float*)d_in[5];
    const float* Wd1 = (const float*)d_in[6];
    const float* bd1 = (const float*)d_in[7];
    const float* Wd2 = (const float*)d_in[8];
    const float* bd2 = (const float*)d_in[9];
    const int* srcIdx = ei;
    const int* dstIdx = ei + NE;
    float* out = (float*)d_out;

    // workspace layout (~46 MB)
    float* fws = (float*)d_ws;
    float* hw1 = fws;                    // NN*64 (reused as 'd' after agg1)
    float* h   = hw1 + NN * CH;          // NN*64
    float* hz  = h + NN * CH;            // NN*32
    float* z   = hz + NN * CL;           // NN*32
    float* dis = z + NN * CL;            // NN
    int* cnt    = (int*)(dis + NN);      // NN
    int* rowptr = cnt + NN;              // NN+1
    int* gcur   = rowptr + NN + 1;       // NB (bucket cursors)
    int* bsum   = gcur + NB;             // 64
    int* csr    = bsum + 64;             // NE (also pair buffer)
    uintptr_t p = (uintptr_t)(csr + NE);
    p = (p + 63) & ~(uintptr_t)63;
    unsigned short* wt1_hi = (unsigned short*)p;   // 64x512
    unsigned short* wt1_lo = wt1_hi + CIN * CH;
    unsigned short* wt2_hi = wt1_lo + CIN * CH;    // 512x64
    unsigned short* wt2_lo = wt2_hi + CIN * CH;
    float* dbuf = hw1;  // alias: hw1 dead after k_agg1

    const int nb_nodes = (NN + 255) / 256;
    const int nb_edges = (NE + 255) / 256;

    k_prep<<<256, 256, 0, stream>>>(W1, Wd2, wt1_hi, wt1_lo, wt2_hi, wt2_lo);

    k_init<<<nb_nodes, 256, 0, stream>>>(cnt, gcur);
    k_deg<<<nb_edges, 256, 0, stream>>>(dstIdx, cnt);
    k_dis<<<nb_nodes, 256, 0, stream>>>(cnt, dis);
    k_scan_block<<<NSCAN, 256, 0, stream>>>(cnt, rowptr, bsum);
    k_scan_top<<<1, 1, 0, stream>>>(bsum, rowptr);
    k_scan_add<<<nb_nodes, 256, 0, stream>>>(rowptr, bsum);
    k_scatA<<<NBLKA, 256, 0, stream>>>(srcIdx, dstIdx, rowptr, gcur, (unsigned int*)csr);
    k_scatB<<<NB, 256, 0, stream>>>(rowptr, csr);

    k_gemm1_mfma<<<(NN + 63) / 64, 256, 0, stream>>>(x, wt1_hi, wt1_lo, dis, hw1);
    k_agg1<<<(NN + 3) / 4, 256, 0, stream>>>(hw1, dis, rowptr, csr, b1, h);
    k_gemm2<<<(NN * 32 + 255) / 256, 256, 0, stream>>>(h, W2, dis, hz);
    k_agg2<<<(NN / 2 + 3) / 4, 256, 0, stream>>>(hz, dis, rowptr, csr, b2, z);
    k_dmlp<<<(NN * CH + 255) / 256, 256, 0, stream>>>(z, Wd1, bd1, dbuf);
    k_dec2<<<((NN + 63) / 64) * 2, 256, 0, stream>>>(dbuf, wt2_hi, wt2_lo, bd2, out);
}

// Round 9
// 527.314 us; speedup vs baseline: 1.0150x; 1.0150x over previous
//
#include <hip/hip_runtime.h>

#define NN 50000
#define NE 1600000
#define CIN 512
#define CH 64
#define CL 32

#define SCAN_CHUNK 1024
#define NSCAN ((NN + SCAN_CHUNK - 1) / SCAN_CHUNK)  // 49

#define BKN 256                                // nodes per bucket
#define NB ((NN + BKN - 1) / BKN)              // 196 buckets
#define CHUNK 8192                             // edges per scatA block
#define NBLKA ((NE + CHUNK - 1) / CHUNK)       // 196
#define SEGCAP 12288                           // bucket segment cap (mean 8192 + 45 sigma)

typedef float f32x4 __attribute__((ext_vector_type(4)));
typedef short bf16x8 __attribute__((ext_vector_type(8)));

// ---------------- bf16 split helpers (RTNE, pure bit ops) ----------------

__device__ inline unsigned short bf_hi(float f) {
    union { float f; unsigned u; } a; a.f = f;
    unsigned r = a.u + 0x7FFFu + ((a.u >> 16) & 1u);
    return (unsigned short)(r >> 16);
}
__device__ inline float bf_to_f(unsigned short h) {
    union { unsigned u; float f; } b; b.u = ((unsigned)h) << 16; return b.f;
}
__device__ inline void split_bf16(float f, unsigned short& hi, unsigned short& lo) {
    hi = bf_hi(f);
    lo = bf_hi(f - bf_to_f(hi));
}
__device__ inline void split4(const float4& v, ushort4& h, ushort4& l) {
    split_bf16(v.x, h.x, l.x); split_bf16(v.y, h.y, l.y);
    split_bf16(v.z, h.z, l.z); split_bf16(v.w, h.w, l.w);
}
__device__ inline void split8(const float4& v0, const float4& v1, bf16x8& h, bf16x8& l) {
    ushort4 h0, l0, h1, l1;
    split4(v0, h0, l0); split4(v1, h1, l1);
    h = (bf16x8){(short)h0.x, (short)h0.y, (short)h0.z, (short)h0.w,
                 (short)h1.x, (short)h1.y, (short)h1.z, (short)h1.w};
    l = (bf16x8){(short)l0.x, (short)l0.y, (short)l0.z, (short)l0.w,
                 (short)l1.x, (short)l1.y, (short)l1.z, (short)l1.w};
}

// XOR-swizzled LDS frag read: planes are [row][64k] bf16, row stride 128B
__device__ inline bf16x8 frag(const char* plane, int row, int koff_bytes) {
    int off = (row * 128 + koff_bytes) ^ ((row & 7) << 4);
    return *(const bf16x8*)(plane + off);
}

// ---------------- weight prep: transpose + split to bf16 hi/lo ----------------

__global__ void k_prep(const float* __restrict__ W1, const float* __restrict__ Wd2,
                       unsigned short* __restrict__ wt1_hi, unsigned short* __restrict__ wt1_lo,
                       unsigned short* __restrict__ wt2_hi, unsigned short* __restrict__ wt2_lo) {
    int id = blockIdx.x * blockDim.x + threadIdx.x;  // 0..65535
    if (id < CIN * CH) {                 // W1: [512][64] -> wt1[n=64][k=512]
        int k = id >> 6, n = id & 63;
        unsigned short h, lo; split_bf16(W1[id], h, lo);
        wt1_hi[n * CIN + k] = h; wt1_lo[n * CIN + k] = lo;
    } else {                             // Wd2: [64][512] -> wt2[n=512][k=64]
        int e = id - CIN * CH;
        int k = e >> 9, n = e & 511;
        unsigned short h, lo; split_bf16(Wd2[e], h, lo);
        wt2_hi[n * CH + k] = h; wt2_lo[n * CH + k] = lo;
    }
}

// ---------------- CSR build ----------------

__global__ void k_init(int* cnt, int* gcur) {
    int i = blockIdx.x * blockDim.x + threadIdx.x;
    if (i < NN) cnt[i] = 0;
    if (i < NB) gcur[i] = 0;
}

__global__ void k_deg(const int* __restrict__ dst, int* __restrict__ cnt) {
    int e = blockIdx.x * blockDim.x + threadIdx.x;
    if (e < NE) atomicAdd(&cnt[dst[e]], 1);
}

__global__ void k_dis(const int* __restrict__ cnt, float* __restrict__ dis) {
    int i = blockIdx.x * blockDim.x + threadIdx.x;
    if (i < NN) dis[i] = rsqrtf((float)(cnt[i] + 1));  // +1 self-loop
}

__global__ void k_scan_block(const int* __restrict__ cnt, int* __restrict__ rowptr,
                             int* __restrict__ bsum) {
    __shared__ int sd[256];
    int t = threadIdx.x, b = blockIdx.x;
    int base = b * SCAN_CHUNK + t * 4;
    int c[4], s = 0;
#pragma unroll
    for (int j = 0; j < 4; j++) {
        int i = base + j;
        c[j] = (i < NN) ? cnt[i] : 0;
        s += c[j];
    }
    sd[t] = s;
    __syncthreads();
    for (int off = 1; off < 256; off <<= 1) {
        int v = (t >= off) ? sd[t - off] : 0;
        __syncthreads();
        sd[t] += v;
        __syncthreads();
    }
    int incl = sd[t];
    int run = incl - s;
#pragma unroll
    for (int j = 0; j < 4; j++) {
        int i = base + j;
        if (i < NN) rowptr[i] = run;
        run += c[j];
    }
    if (t == 255) bsum[b] = incl;
}

__global__ void k_scan_top(int* bsum, int* rowptr) {
    int run = 0;
    for (int b = 0; b < NSCAN; b++) {
        int v = bsum[b];
        bsum[b] = run;
        run += v;
    }
    rowptr[NN] = run;
}

__global__ void k_scan_add(int* rowptr, const int* __restrict__ bsum) {
    int i = blockIdx.x * blockDim.x + threadIdx.x;
    if (i < NN) rowptr[i] += bsum[i >> 10];
}

// ---- binned scatter phase A: bucket-sort edge pairs into csr segments ----
// pair u32 = (dst<<16) | src  (both < 65536). pairbuf aliases csr.

__launch_bounds__(256)
__global__ void k_scatA(const int* __restrict__ srcIdx, const int* __restrict__ dstIdx,
                        const int* __restrict__ rowptr, int* __restrict__ gcur,
                        unsigned int* __restrict__ pairbuf) {
    __shared__ unsigned int stage[CHUNK];          // 32 KB
    __shared__ unsigned char bids[CHUNK];          // 8 KB
    __shared__ int hist[256], lbase[256], runcur[256], gbase[256];
    const int t = threadIdx.x;
    const int e0 = blockIdx.x * CHUNK;
    const int tot = min(NE - e0, CHUNK);

    hist[t] = 0; runcur[t] = 0;
    __syncthreads();

    unsigned int pr[CHUNK / 256];
    unsigned char bk[CHUNK / 256];
#pragma unroll
    for (int k = 0; k < CHUNK / 256; ++k) {
        int e = e0 + k * 256 + t;
        if (e < NE) {
            int s = srcIdx[e], d = dstIdx[e];
            pr[k] = ((unsigned)d << 16) | (unsigned)s;
            bk[k] = (unsigned char)(d >> 8);
            atomicAdd(&hist[bk[k]], 1);
        }
    }
    __syncthreads();
    // exclusive scan of hist over 256 entries
    int cb = hist[t];
    lbase[t] = cb;
    __syncthreads();
    for (int off = 1; off < 256; off <<= 1) {
        int v = (t >= off) ? lbase[t - off] : 0;
        __syncthreads();
        lbase[t] += v;
        __syncthreads();
    }
    int excl = lbase[t] - cb;
    __syncthreads();
    lbase[t] = excl;
    // reserve global run per bucket
    if (t < NB) {
        int base = rowptr[t * BKN];
        gbase[t] = base + (cb ? atomicAdd(&gcur[t], cb) : 0);
    }
    __syncthreads();
    // pass 2: place into stage bucket-sorted
#pragma unroll
    for (int k = 0; k < CHUNK / 256; ++k) {
        int e = e0 + k * 256 + t;
        if (e < NE) {
            int b = bk[k];
            int off = lbase[b] + atomicAdd(&runcur[b], 1);
            stage[off] = pr[k];
            bids[off] = (unsigned char)b;
        }
    }
    __syncthreads();
    // copy out: consecutive i within a bucket -> consecutive global positions
    for (int i = t; i < tot; i += 256) {
        int b = bids[i];
        pairbuf[gbase[b] + (i - lbase[b])] = stage[i];
    }
}

// ---- binned scatter phase B: node-level ordering within bucket, in-place ----

__launch_bounds__(256)
__global__ void k_scatB(const int* __restrict__ rowptr, int* __restrict__ csr) {
    __shared__ int lcsr[SEGCAP];       // 48 KB
    __shared__ int lrp[BKN + 1];
    __shared__ int lcur[BKN];
    const int t = threadIdx.x, b = blockIdx.x;
    const int n0 = b * BKN;
    const int nn = min(BKN, NN - n0);
    for (int i = t; i <= nn; i += 256) lrp[i] = rowptr[n0 + i];
    if (t < BKN) lcur[t] = 0;
    __syncthreads();
    const int p0 = lrp[0], p1 = lrp[nn];
    const int cnt = p1 - p0;
    for (int i = p0 + t; i < p1; i += 256) {
        unsigned int pr = ((const unsigned int*)csr)[i];
        int dL = (int)(pr >> 16) - n0;
        int slot = (lrp[dL] - p0) + atomicAdd(&lcur[dL], 1);
        lcsr[slot] = (int)(pr & 0xFFFFu);
    }
    __syncthreads();
    for (int i = t; i < cnt; i += 256) csr[p0 + i] = lcsr[i];
}

// ---------------- GEMM1 (MFMA split-bf16): hw1s = (x @ W1) * dis[row] ----------------
// M=50000 (64/block), N=64, K=512 (chunks of 64)

__launch_bounds__(256)
__global__ void k_gemm1_mfma(const float* __restrict__ x,
                             const unsigned short* __restrict__ wt_hi,
                             const unsigned short* __restrict__ wt_lo,
                             const float* __restrict__ dis,
                             float* __restrict__ hw1) {
    __shared__ alignas(16) char Ahi[8192], Alo[8192], Bhi[8192], Blo[8192];
    const int t = threadIdx.x;
    const int w = t >> 6, l = t & 63;
    const int row0 = blockIdx.x * 64;
    const int r = t >> 2;            // staging row 0..63
    const int kq = (t & 3) * 16;     // staging k start (elems)

    f32x4 zero4 = {0.f, 0.f, 0.f, 0.f};
    f32x4 acc[4];
#pragma unroll
    for (int f = 0; f < 4; ++f) acc[f] = zero4;

    const bool inb = (row0 + r) < NN;

    for (int kc = 0; kc < CIN; kc += 64) {
        // stage A: x tile 64x64 fp32 -> hi/lo bf16 planes (swizzled)
        const float* xp = x + (row0 + r) * CIN + kc + kq;
#pragma unroll
        for (int j = 0; j < 4; ++j) {
            float4 v = inb ? *(const float4*)(xp + j * 4) : make_float4(0.f, 0.f, 0.f, 0.f);
            ushort4 h4, l4; split4(v, h4, l4);
            int so = (r * 128 + (kq + j * 4) * 2) ^ ((r & 7) << 4);
            *(ushort4*)(Ahi + so) = h4;
            *(ushort4*)(Alo + so) = l4;
        }
        // stage B: wt1 tile [n=64][k=64] bf16 hi/lo (swizzled)
        {
            const char* bh = (const char*)wt_hi;
            const char* bl = (const char*)wt_lo;
            int kb = (t & 3) * 32;   // byte offset within 128B chunk-row
#pragma unroll
            for (int j = 0; j < 2; ++j) {
                int srcoff = r * (CIN * 2) + kc * 2 + kb + j * 16;
                int so = (r * 128 + kb + j * 16) ^ ((r & 7) << 4);
                *(int4*)(Bhi + so) = *(const int4*)(bh + srcoff);
                *(int4*)(Blo + so) = *(const int4*)(bl + srcoff);
            }
        }
        __syncthreads();
#pragma unroll
        for (int ks = 0; ks < 2; ++ks) {
            int kb = ks * 64 + (l >> 4) * 16;
            bf16x8 aH = frag(Ahi, w * 16 + (l & 15), kb);
            bf16x8 aL = frag(Alo, w * 16 + (l & 15), kb);
#pragma unroll
            for (int f = 0; f < 4; ++f) {
                bf16x8 bH = frag(Bhi, f * 16 + (l & 15), kb);
                bf16x8 bL = frag(Blo, f * 16 + (l & 15), kb);
                acc[f] = __builtin_amdgcn_mfma_f32_16x16x32_bf16(aH, bH, acc[f], 0, 0, 0);
                acc[f] = __builtin_amdgcn_mfma_f32_16x16x32_bf16(aL, bH, acc[f], 0, 0, 0);
                acc[f] = __builtin_amdgcn_mfma_f32_16x16x32_bf16(aH, bL, acc[f], 0, 0, 0);
            }
        }
        __syncthreads();
    }
    // epilogue: C/D layout col=lane&15, row=(lane>>4)*4+reg; pre-scale by dis[row]
#pragma unroll
    for (int i = 0; i < 4; ++i) {
        int row = row0 + w * 16 + (l >> 4) * 4 + i;
        if (row < NN) {
            float di = dis[row];
#pragma unroll
            for (int f = 0; f < 4; ++f)
                hw1[row * CH + f * 16 + (l & 15)] = di * acc[f][i];
        }
    }
}

// ---------------- Aggregation 1: h = relu(dis[i]*sum(hw1s) + b1), H=64 ----------------

__launch_bounds__(256)
__global__ void k_agg1(const float* __restrict__ hw1s, const float* __restrict__ dis,
                       const int* __restrict__ rowptr, const int* __restrict__ csr,
                       const float* __restrict__ b1, float* __restrict__ h) {
    int i = blockIdx.x * 4 + (threadIdx.x >> 6);
    if (i >= NN) return;
    int c = threadIdx.x & 63;
    float a0 = hw1s[i * CH + c];  // self-loop term (pre-scaled): dis[i]*hw1[i]
    float a1 = 0.f, a2 = 0.f, a3 = 0.f, a4 = 0.f, a5 = 0.f, a6 = 0.f, a7 = 0.f;
    int p = rowptr[i], p1 = rowptr[i + 1];
    for (; p + 8 <= p1; p += 8) {
        int s0 = csr[p + 0], s1 = csr[p + 1], s2 = csr[p + 2], s3 = csr[p + 3];
        int s4 = csr[p + 4], s5 = csr[p + 5], s6 = csr[p + 6], s7 = csr[p + 7];
        a0 += hw1s[s0 * CH + c]; a1 += hw1s[s1 * CH + c];
        a2 += hw1s[s2 * CH + c]; a3 += hw1s[s3 * CH + c];
        a4 += hw1s[s4 * CH + c]; a5 += hw1s[s5 * CH + c];
        a6 += hw1s[s6 * CH + c]; a7 += hw1s[s7 * CH + c];
    }
    for (; p < p1; ++p) a0 += hw1s[csr[p] * CH + c];
    float sum = ((a0 + a1) + (a2 + a3)) + ((a4 + a5) + (a6 + a7));
    float v = dis[i] * sum + b1[c];
    h[i * CH + c] = v > 0.f ? v : 0.f;
}

// ---------------- GEMM2: hzs = (h @ W2) * dis[n]  (50000x64 @ 64x32) ----------------

__global__ void k_gemm2(const float* __restrict__ h, const float* __restrict__ W2,
                        const float* __restrict__ dis, float* __restrict__ hz) {
    int t = blockIdx.x * blockDim.x + threadIdx.x;
    int n = t >> 5, c = t & 31;
    if (n >= NN) return;
    float acc = 0.f;
#pragma unroll
    for (int k = 0; k < CH; k++) acc = fmaf(h[n * CH + k], W2[k * CL + c], acc);
    hz[n * CL + c] = acc * dis[n];
}

// ---------------- Aggregation 2: z = relu(dis[i]*sum(hzs) + b2), H=32 ----------------

__launch_bounds__(256)
__global__ void k_agg2(const float* __restrict__ hzs, const float* __restrict__ dis,
                       const int* __restrict__ rowptr, const int* __restrict__ csr,
                       const float* __restrict__ b2, float* __restrict__ z) {
    int wave = blockIdx.x * 4 + (threadIdx.x >> 6);
    int half = (threadIdx.x >> 5) & 1;
    int i = wave * 2 + half;
    if (i >= NN) return;
    int c = threadIdx.x & 31;
    float a0 = hzs[i * CL + c];
    float a1 = 0.f, a2 = 0.f, a3 = 0.f, a4 = 0.f, a5 = 0.f, a6 = 0.f, a7 = 0.f;
    int p = rowptr[i], p1 = rowptr[i + 1];
    for (; p + 8 <= p1; p += 8) {
        int s0 = csr[p + 0], s1 = csr[p + 1], s2 = csr[p + 2], s3 = csr[p + 3];
        int s4 = csr[p + 4], s5 = csr[p + 5], s6 = csr[p + 6], s7 = csr[p + 7];
        a0 += hzs[s0 * CL + c]; a1 += hzs[s1 * CL + c];
        a2 += hzs[s2 * CL + c]; a3 += hzs[s3 * CL + c];
        a4 += hzs[s4 * CL + c]; a5 += hzs[s5 * CL + c];
        a6 += hzs[s6 * CL + c]; a7 += hzs[s7 * CL + c];
    }
    for (; p < p1; ++p) a0 += hzs[csr[p] * CL + c];
    float sum = ((a0 + a1) + (a2 + a3)) + ((a4 + a5) + (a6 + a7));
    float v = dis[i] * sum + b2[c];
    z[i * CL + c] = v > 0.f ? v : 0.f;
}

// ---------------- Decoder layer 1: d = relu(z @ Wd1 + bd1) ----------------

__global__ void k_dmlp(const float* __restrict__ z, const float* __restrict__ Wd1,
                       const float* __restrict__ bd1, float* __restrict__ dout) {
    int g = blockIdx.x * blockDim.x + threadIdx.x;
    int n = g >> 6, c = g & 63;
    if (n >= NN) return;
    float acc = bd1[c];
    const float* zp = z + n * CL;
#pragma unroll
    for (int k = 0; k < CL; ++k) acc = fmaf(zp[k], Wd1[k * CH + c], acc);
    dout[n * CH + c] = acc > 0.f ? acc : 0.f;
}

// ---------------- Decoder layer 2 (MFMA split-bf16) + sigmoid ----------------
// M=50000 (64/block), N=512 (2 tiles of 256), K=64. A/B direct from global;
// epilogue transposes each wave's 16x256 sub-tile through wave-private LDS
// (no barriers) so stores are 512B-contiguous float4 runs instead of 64-B
// scattered segments (the ~1.3 TB/s store-granularity wall).

__launch_bounds__(256)
__global__ void k_dec2(const float* __restrict__ d,
                       const unsigned short* __restrict__ wt2_hi,
                       const unsigned short* __restrict__ wt2_lo,
                       const float* __restrict__ bd2,
                       float* __restrict__ out) {
    __shared__ float sb[4][16 * 132];   // per-wave transpose buffer, 132-f padded rows
    const int t = threadIdx.x;
    const int w = t >> 6, l = t & 63;
    const int mt = blockIdx.x >> 1, nt = blockIdx.x & 1;
    const int row0 = mt * 64, col0 = nt * 256;
    const int lq = l >> 4, lr = l & 15;
    float* wbuf = sb[w];

    // A fragments direct from global: lane holds A[m=lr][k=ks*32+lq*8 .. +8]
    const int arow = row0 + w * 16 + lr;
    const bool inb = arow < NN;
    bf16x8 aH[2], aL[2];
#pragma unroll
    for (int ks = 0; ks < 2; ++ks) {
        const float* ap = d + arow * CH + ks * 32 + lq * 8;
        float4 v0 = inb ? *(const float4*)ap : make_float4(0.f, 0.f, 0.f, 0.f);
        float4 v1 = inb ? *(const float4*)(ap + 4) : make_float4(0.f, 0.f, 0.f, 0.f);
        split8(v0, v1, aH[ks], aL[ks]);
    }

    f32x4 zero4 = {0.f, 0.f, 0.f, 0.f};
    f32x4 acc[16];
#pragma unroll
    for (int f = 0; f < 16; ++f) acc[f] = zero4;

#pragma unroll
    for (int f = 0; f < 16; ++f) {
        const int brow = col0 + f * 16 + lr;
#pragma unroll
        for (int ks = 0; ks < 2; ++ks) {
            const int boff = brow * CH + ks * 32 + lq * 8;
            bf16x8 bH = *(const bf16x8*)(wt2_hi + boff);
            bf16x8 bL = *(const bf16x8*)(wt2_lo + boff);
            acc[f] = __builtin_amdgcn_mfma_f32_16x16x32_bf16(aH[ks], bH, acc[f], 0, 0, 0);
            acc[f] = __builtin_amdgcn_mfma_f32_16x16x32_bf16(aL[ks], bH, acc[f], 0, 0, 0);
            acc[f] = __builtin_amdgcn_mfma_f32_16x16x32_bf16(aH[ks], bL, acc[f], 0, 0, 0);
        }
    }

    // epilogue: two 128-col halves; wave-private LDS transpose, contiguous stores
#pragma unroll
    for (int hh = 0; hh < 2; ++hh) {
        // stage: sigmoid(acc + bias) -> wbuf[row][colInHalf]
#pragma unroll
        for (int fo = 0; fo < 8; ++fo) {
            int f = hh * 8 + fo;
            float bias = bd2[col0 + f * 16 + lr];
#pragma unroll
            for (int i = 0; i < 4; ++i) {
                float v = acc[f][i] + bias;
                wbuf[(lq * 4 + i) * 132 + fo * 16 + lr] = 1.f / (1.f + __expf(-v));
            }
        }
        // drain: row-linear float4 stores (wave-internal DS ordering, no barrier)
#pragma unroll
        for (int j = 0; j < 8; ++j) {
            int r = j * 2 + (l >> 5);
            int cc = (l & 31) * 4;
            int row = row0 + w * 16 + r;
            if (row < NN) {
                float4 v = *(const float4*)&wbuf[r * 132 + cc];
                *(float4*)&out[row * CIN + col0 + hh * 128 + cc] = v;
            }
        }
    }
}

// ---------------- launch ----------------

extern "C" void kernel_launch(void* const* d_in, const int* in_sizes, int n_in,
                              void* d_out, int out_size, void* d_ws, size_t ws_size,
                              hipStream_t stream) {
    const float* x   = (const float*)d_in[0];
    const int*   ei  = (const int*)d_in[1];
    const float* W1  = (const float*)d_in[2];
    const float* b1  = (const float*)d_in[3];
    const float* W2  = (const float*)d_in[4];
    const float* b2  = (const float*)d_in[5];
    const float* Wd1 = (const float*)d_in[6];
    const float* bd1 = (const float*)d_in[7];
    const float* Wd2 = (const float*)d_in[8];
    const float* bd2 = (const float*)d_in[9];
    const int* srcIdx = ei;
    const int* dstIdx = ei + NE;
    float* out = (float*)d_out;

    // workspace layout (~46 MB)
    float* fws = (float*)d_ws;
    float* hw1 = fws;                    // NN*64 (reused as 'd' after agg1)
    float* h   = hw1 + NN * CH;          // NN*64
    float* hz  = h + NN * CH;            // NN*32
    float* z   = hz + NN * CL;           // NN*32
    float* dis = z + NN * CL;            // NN
    int* cnt    = (int*)(dis + NN);      // NN
    int* rowptr = cnt + NN;              // NN+1
    int* gcur   = rowptr + NN + 1;       // NB (bucket cursors)
    int* bsum   = gcur + NB;             // 64
    int* csr    = bsum + 64;             // NE (also pair buffer)
    uintptr_t p = (uintptr_t)(csr + NE);
    p = (p + 63) & ~(uintptr_t)63;
    unsigned short* wt1_hi = (unsigned short*)p;   // 64x512
    unsigned short* wt1_lo = wt1_hi + CIN * CH;
    unsigned short* wt2_hi = wt1_lo + CIN * CH;    // 512x64
    unsigned short* wt2_lo = wt2_hi + CIN * CH;
    float* dbuf = hw1;  // alias: hw1 dead after k_agg1

    const int nb_nodes = (NN + 255) / 256;
    const int nb_edges = (NE + 255) / 256;

    k_prep<<<256, 256, 0, stream>>>(W1, Wd2, wt1_hi, wt1_lo, wt2_hi, wt2_lo);

    k_init<<<nb_nodes, 256, 0, stream>>>(cnt, gcur);
    k_deg<<<nb_edges, 256, 0, stream>>>(dstIdx, cnt);
    k_dis<<<nb_nodes, 256, 0, stream>>>(cnt, dis);
    k_scan_block<<<NSCAN, 256, 0, stream>>>(cnt, rowptr, bsum);
    k_scan_top<<<1, 1, 0, stream>>>(bsum, rowptr);
    k_scan_add<<<nb_nodes, 256, 0, stream>>>(rowptr, bsum);
    k_scatA<<<NBLKA, 256, 0, stream>>>(srcIdx, dstIdx, rowptr, gcur, (unsigned int*)csr);
    k_scatB<<<NB, 256, 0, stream>>>(rowptr, csr);

    k_gemm1_mfma<<<(NN + 63) / 64, 256, 0, stream>>>(x, wt1_hi, wt1_lo, dis, hw1);
    k_agg1<<<(NN + 3) / 4, 256, 0, stream>>>(hw1, dis, rowptr, csr, b1, h);
    k_gemm2<<<(NN * 32 + 255) / 256, 256, 0, stream>>>(h, W2, dis, hz);
    k_agg2<<<(NN / 2 + 3) / 4, 256, 0, stream>>>(hz, dis, rowptr, csr, b2, z);
    k_dmlp<<<(NN * CH + 255) / 256, 256, 0, stream>>>(z, Wd1, bd1, dbuf);
    k_dec2<<<((NN + 63) / 64) * 2, 256, 0, stream>>>(dbuf, wt2_hi, wt2_lo, bd2, out);
}

// Round 10
// 492.692 us; speedup vs baseline: 1.0863x; 1.0703x over previous
//
#include <hip/hip_runtime.h>

#define NN 50000
#define NE 1600000
#define CIN 512
#define CH 64
#define CL 32

#define SCAN_CHUNK 1024
#define NSCAN ((NN + SCAN_CHUNK - 1) / SCAN_CHUNK)  // 49

#define BKN 256                                // nodes per bucket
#define NB ((NN + BKN - 1) / BKN)              // 196 buckets
#define CHUNK 8192                             // edges per scatA block
#define NBLKA ((NE + CHUNK - 1) / CHUNK)       // 196
#define SEGCAP 12288                           // bucket segment cap (mean 8192 + 45 sigma)

typedef float f32x4 __attribute__((ext_vector_type(4)));
typedef short bf16x8 __attribute__((ext_vector_type(8)));

// ---------------- bf16 split helpers (RTNE, pure bit ops) ----------------

__device__ inline unsigned short bf_hi(float f) {
    union { float f; unsigned u; } a; a.f = f;
    unsigned r = a.u + 0x7FFFu + ((a.u >> 16) & 1u);
    return (unsigned short)(r >> 16);
}
__device__ inline float bf_to_f(unsigned short h) {
    union { unsigned u; float f; } b; b.u = ((unsigned)h) << 16; return b.f;
}
__device__ inline void split_bf16(float f, unsigned short& hi, unsigned short& lo) {
    hi = bf_hi(f);
    lo = bf_hi(f - bf_to_f(hi));
}
__device__ inline void split4(const float4& v, ushort4& h, ushort4& l) {
    split_bf16(v.x, h.x, l.x); split_bf16(v.y, h.y, l.y);
    split_bf16(v.z, h.z, l.z); split_bf16(v.w, h.w, l.w);
}
__device__ inline void split8(const float4& v0, const float4& v1, bf16x8& h, bf16x8& l) {
    ushort4 h0, l0, h1, l1;
    split4(v0, h0, l0); split4(v1, h1, l1);
    h = (bf16x8){(short)h0.x, (short)h0.y, (short)h0.z, (short)h0.w,
                 (short)h1.x, (short)h1.y, (short)h1.z, (short)h1.w};
    l = (bf16x8){(short)l0.x, (short)l0.y, (short)l0.z, (short)l0.w,
                 (short)l1.x, (short)l1.y, (short)l1.z, (short)l1.w};
}

// XOR-swizzled LDS frag read: planes are [row][64k] bf16, row stride 128B
__device__ inline bf16x8 frag(const char* plane, int row, int koff_bytes) {
    int off = (row * 128 + koff_bytes) ^ ((row & 7) << 4);
    return *(const bf16x8*)(plane + off);
}

// ---------------- weight prep: transpose + split to bf16 hi/lo ----------------

__global__ void k_prep(const float* __restrict__ W1, const float* __restrict__ Wd2,
                       unsigned short* __restrict__ wt1_hi, unsigned short* __restrict__ wt1_lo,
                       unsigned short* __restrict__ wt2_hi, unsigned short* __restrict__ wt2_lo) {
    int id = blockIdx.x * blockDim.x + threadIdx.x;  // 0..65535
    if (id < CIN * CH) {                 // W1: [512][64] -> wt1[n=64][k=512]
        int k = id >> 6, n = id & 63;
        unsigned short h, lo; split_bf16(W1[id], h, lo);
        wt1_hi[n * CIN + k] = h; wt1_lo[n * CIN + k] = lo;
    } else {                             // Wd2: [64][512] -> wt2[n=512][k=64]
        int e = id - CIN * CH;
        int k = e >> 9, n = e & 511;
        unsigned short h, lo; split_bf16(Wd2[e], h, lo);
        wt2_hi[n * CH + k] = h; wt2_lo[n * CH + k] = lo;
    }
}

// ---------------- CSR build ----------------

__global__ void k_init(int* cnt, int* gcur) {
    int i = blockIdx.x * blockDim.x + threadIdx.x;
    if (i < NN) cnt[i] = 0;
    if (i < NB) gcur[i] = 0;
}

__global__ void k_deg(const int* __restrict__ dst, int* __restrict__ cnt) {
    int e = blockIdx.x * blockDim.x + threadIdx.x;
    if (e < NE) atomicAdd(&cnt[dst[e]], 1);
}

__global__ void k_dis(const int* __restrict__ cnt, float* __restrict__ dis) {
    int i = blockIdx.x * blockDim.x + threadIdx.x;
    if (i < NN) dis[i] = rsqrtf((float)(cnt[i] + 1));  // +1 self-loop
}

__global__ void k_scan_block(const int* __restrict__ cnt, int* __restrict__ rowptr,
                             int* __restrict__ bsum) {
    __shared__ int sd[256];
    int t = threadIdx.x, b = blockIdx.x;
    int base = b * SCAN_CHUNK + t * 4;
    int c[4], s = 0;
#pragma unroll
    for (int j = 0; j < 4; j++) {
        int i = base + j;
        c[j] = (i < NN) ? cnt[i] : 0;
        s += c[j];
    }
    sd[t] = s;
    __syncthreads();
    for (int off = 1; off < 256; off <<= 1) {
        int v = (t >= off) ? sd[t - off] : 0;
        __syncthreads();
        sd[t] += v;
        __syncthreads();
    }
    int incl = sd[t];
    int run = incl - s;
#pragma unroll
    for (int j = 0; j < 4; j++) {
        int i = base + j;
        if (i < NN) rowptr[i] = run;
        run += c[j];
    }
    if (t == 255) bsum[b] = incl;
}

__global__ void k_scan_top(int* bsum, int* rowptr) {
    int run = 0;
    for (int b = 0; b < NSCAN; b++) {
        int v = bsum[b];
        bsum[b] = run;
        run += v;
    }
    rowptr[NN] = run;
}

__global__ void k_scan_add(int* rowptr, const int* __restrict__ bsum) {
    int i = blockIdx.x * blockDim.x + threadIdx.x;
    if (i < NN) rowptr[i] += bsum[i >> 10];
}

// ---- binned scatter phase A: bucket-sort edge pairs into csr segments ----
// pair u32 = (dst<<16) | src  (both < 65536). pairbuf aliases csr.

__launch_bounds__(256)
__global__ void k_scatA(const int* __restrict__ srcIdx, const int* __restrict__ dstIdx,
                        const int* __restrict__ rowptr, int* __restrict__ gcur,
                        unsigned int* __restrict__ pairbuf) {
    __shared__ unsigned int stage[CHUNK];          // 32 KB
    __shared__ unsigned char bids[CHUNK];          // 8 KB
    __shared__ int hist[256], lbase[256], runcur[256], gbase[256];
    const int t = threadIdx.x;
    const int e0 = blockIdx.x * CHUNK;
    const int tot = min(NE - e0, CHUNK);

    hist[t] = 0; runcur[t] = 0;
    __syncthreads();

    unsigned int pr[CHUNK / 256];
    unsigned char bk[CHUNK / 256];
#pragma unroll
    for (int k = 0; k < CHUNK / 256; ++k) {
        int e = e0 + k * 256 + t;
        if (e < NE) {
            int s = srcIdx[e], d = dstIdx[e];
            pr[k] = ((unsigned)d << 16) | (unsigned)s;
            bk[k] = (unsigned char)(d >> 8);
            atomicAdd(&hist[bk[k]], 1);
        }
    }
    __syncthreads();
    // exclusive scan of hist over 256 entries
    int cb = hist[t];
    lbase[t] = cb;
    __syncthreads();
    for (int off = 1; off < 256; off <<= 1) {
        int v = (t >= off) ? lbase[t - off] : 0;
        __syncthreads();
        lbase[t] += v;
        __syncthreads();
    }
    int excl = lbase[t] - cb;
    __syncthreads();
    lbase[t] = excl;
    // reserve global run per bucket
    if (t < NB) {
        int base = rowptr[t * BKN];
        gbase[t] = base + (cb ? atomicAdd(&gcur[t], cb) : 0);
    }
    __syncthreads();
    // pass 2: place into stage bucket-sorted
#pragma unroll
    for (int k = 0; k < CHUNK / 256; ++k) {
        int e = e0 + k * 256 + t;
        if (e < NE) {
            int b = bk[k];
            int off = lbase[b] + atomicAdd(&runcur[b], 1);
            stage[off] = pr[k];
            bids[off] = (unsigned char)b;
        }
    }
    __syncthreads();
    // copy out: consecutive i within a bucket -> consecutive global positions
    for (int i = t; i < tot; i += 256) {
        int b = bids[i];
        pairbuf[gbase[b] + (i - lbase[b])] = stage[i];
    }
}

// ---- binned scatter phase B: node-level ordering within bucket, in-place ----

__launch_bounds__(256)
__global__ void k_scatB(const int* __restrict__ rowptr, int* __restrict__ csr) {
    __shared__ int lcsr[SEGCAP];       // 48 KB
    __shared__ int lrp[BKN + 1];
    __shared__ int lcur[BKN];
    const int t = threadIdx.x, b = blockIdx.x;
    const int n0 = b * BKN;
    const int nn = min(BKN, NN - n0);
    for (int i = t; i <= nn; i += 256) lrp[i] = rowptr[n0 + i];
    if (t < BKN) lcur[t] = 0;
    __syncthreads();
    const int p0 = lrp[0], p1 = lrp[nn];
    const int cnt = p1 - p0;
    for (int i = p0 + t; i < p1; i += 256) {
        unsigned int pr = ((const unsigned int*)csr)[i];
        int dL = (int)(pr >> 16) - n0;
        int slot = (lrp[dL] - p0) + atomicAdd(&lcur[dL], 1);
        lcsr[slot] = (int)(pr & 0xFFFFu);
    }
    __syncthreads();
    for (int i = t; i < cnt; i += 256) csr[p0 + i] = lcsr[i];
}

// ---------------- GEMM1 (MFMA split-bf16): hw1s = (x @ W1) * dis[row] ----------------
// M=50000 (64/block), N=64, K=512 (chunks of 64)

__launch_bounds__(256)
__global__ void k_gemm1_mfma(const float* __restrict__ x,
                             const unsigned short* __restrict__ wt_hi,
                             const unsigned short* __restrict__ wt_lo,
                             const float* __restrict__ dis,
                             float* __restrict__ hw1) {
    __shared__ alignas(16) char Ahi[8192], Alo[8192], Bhi[8192], Blo[8192];
    const int t = threadIdx.x;
    const int w = t >> 6, l = t & 63;
    const int row0 = blockIdx.x * 64;
    const int r = t >> 2;            // staging row 0..63
    const int kq = (t & 3) * 16;     // staging k start (elems)

    f32x4 zero4 = {0.f, 0.f, 0.f, 0.f};
    f32x4 acc[4];
#pragma unroll
    for (int f = 0; f < 4; ++f) acc[f] = zero4;

    const bool inb = (row0 + r) < NN;

    for (int kc = 0; kc < CIN; kc += 64) {
        // stage A: x tile 64x64 fp32 -> hi/lo bf16 planes (swizzled)
        const float* xp = x + (row0 + r) * CIN + kc + kq;
#pragma unroll
        for (int j = 0; j < 4; ++j) {
            float4 v = inb ? *(const float4*)(xp + j * 4) : make_float4(0.f, 0.f, 0.f, 0.f);
            ushort4 h4, l4; split4(v, h4, l4);
            int so = (r * 128 + (kq + j * 4) * 2) ^ ((r & 7) << 4);
            *(ushort4*)(Ahi + so) = h4;
            *(ushort4*)(Alo + so) = l4;
        }
        // stage B: wt1 tile [n=64][k=64] bf16 hi/lo (swizzled)
        {
            const char* bh = (const char*)wt_hi;
            const char* bl = (const char*)wt_lo;
            int kb = (t & 3) * 32;   // byte offset within 128B chunk-row
#pragma unroll
            for (int j = 0; j < 2; ++j) {
                int srcoff = r * (CIN * 2) + kc * 2 + kb + j * 16;
                int so = (r * 128 + kb + j * 16) ^ ((r & 7) << 4);
                *(int4*)(Bhi + so) = *(const int4*)(bh + srcoff);
                *(int4*)(Blo + so) = *(const int4*)(bl + srcoff);
            }
        }
        __syncthreads();
#pragma unroll
        for (int ks = 0; ks < 2; ++ks) {
            int kb = ks * 64 + (l >> 4) * 16;
            bf16x8 aH = frag(Ahi, w * 16 + (l & 15), kb);
            bf16x8 aL = frag(Alo, w * 16 + (l & 15), kb);
#pragma unroll
            for (int f = 0; f < 4; ++f) {
                bf16x8 bH = frag(Bhi, f * 16 + (l & 15), kb);
                bf16x8 bL = frag(Blo, f * 16 + (l & 15), kb);
                acc[f] = __builtin_amdgcn_mfma_f32_16x16x32_bf16(aH, bH, acc[f], 0, 0, 0);
                acc[f] = __builtin_amdgcn_mfma_f32_16x16x32_bf16(aL, bH, acc[f], 0, 0, 0);
                acc[f] = __builtin_amdgcn_mfma_f32_16x16x32_bf16(aH, bL, acc[f], 0, 0, 0);
            }
        }
        __syncthreads();
    }
    // epilogue: C/D layout col=lane&15, row=(lane>>4)*4+reg; pre-scale by dis[row]
#pragma unroll
    for (int i = 0; i < 4; ++i) {
        int row = row0 + w * 16 + (l >> 4) * 4 + i;
        if (row < NN) {
            float di = dis[row];
#pragma unroll
            for (int f = 0; f < 4; ++f)
                hw1[row * CH + f * 16 + (l & 15)] = di * acc[f][i];
        }
    }
}

// ---------------- Aggregation 1: h = relu(dis[i]*sum(hw1s) + b1), H=64 ----------------

__launch_bounds__(256)
__global__ void k_agg1(const float* __restrict__ hw1s, const float* __restrict__ dis,
                       const int* __restrict__ rowptr, const int* __restrict__ csr,
                       const float* __restrict__ b1, float* __restrict__ h) {
    int i = blockIdx.x * 4 + (threadIdx.x >> 6);
    if (i >= NN) return;
    int c = threadIdx.x & 63;
    float a0 = hw1s[i * CH + c];  // self-loop term (pre-scaled): dis[i]*hw1[i]
    float a1 = 0.f, a2 = 0.f, a3 = 0.f, a4 = 0.f, a5 = 0.f, a6 = 0.f, a7 = 0.f;
    int p = rowptr[i], p1 = rowptr[i + 1];
    for (; p + 8 <= p1; p += 8) {
        int s0 = csr[p + 0], s1 = csr[p + 1], s2 = csr[p + 2], s3 = csr[p + 3];
        int s4 = csr[p + 4], s5 = csr[p + 5], s6 = csr[p + 6], s7 = csr[p + 7];
        a0 += hw1s[s0 * CH + c]; a1 += hw1s[s1 * CH + c];
        a2 += hw1s[s2 * CH + c]; a3 += hw1s[s3 * CH + c];
        a4 += hw1s[s4 * CH + c]; a5 += hw1s[s5 * CH + c];
        a6 += hw1s[s6 * CH + c]; a7 += hw1s[s7 * CH + c];
    }
    for (; p < p1; ++p) a0 += hw1s[csr[p] * CH + c];
    float sum = ((a0 + a1) + (a2 + a3)) + ((a4 + a5) + (a6 + a7));
    float v = dis[i] * sum + b1[c];
    h[i * CH + c] = v > 0.f ? v : 0.f;
}

// ---------------- GEMM2: hzs = (h @ W2) * dis[n]  (50000x64 @ 64x32) ----------------

__global__ void k_gemm2(const float* __restrict__ h, const float* __restrict__ W2,
                        const float* __restrict__ dis, float* __restrict__ hz) {
    int t = blockIdx.x * blockDim.x + threadIdx.x;
    int n = t >> 5, c = t & 31;
    if (n >= NN) return;
    float acc = 0.f;
#pragma unroll
    for (int k = 0; k < CH; k++) acc = fmaf(h[n * CH + k], W2[k * CL + c], acc);
    hz[n * CL + c] = acc * dis[n];
}

// ---------------- Aggregation 2: z = relu(dis[i]*sum(hzs) + b2), H=32 ----------------

__launch_bounds__(256)
__global__ void k_agg2(const float* __restrict__ hzs, const float* __restrict__ dis,
                       const int* __restrict__ rowptr, const int* __restrict__ csr,
                       const float* __restrict__ b2, float* __restrict__ z) {
    int wave = blockIdx.x * 4 + (threadIdx.x >> 6);
    int half = (threadIdx.x >> 5) & 1;
    int i = wave * 2 + half;
    if (i >= NN) return;
    int c = threadIdx.x & 31;
    float a0 = hzs[i * CL + c];
    float a1 = 0.f, a2 = 0.f, a3 = 0.f, a4 = 0.f, a5 = 0.f, a6 = 0.f, a7 = 0.f;
    int p = rowptr[i], p1 = rowptr[i + 1];
    for (; p + 8 <= p1; p += 8) {
        int s0 = csr[p + 0], s1 = csr[p + 1], s2 = csr[p + 2], s3 = csr[p + 3];
        int s4 = csr[p + 4], s5 = csr[p + 5], s6 = csr[p + 6], s7 = csr[p + 7];
        a0 += hzs[s0 * CL + c]; a1 += hzs[s1 * CL + c];
        a2 += hzs[s2 * CL + c]; a3 += hzs[s3 * CL + c];
        a4 += hzs[s4 * CL + c]; a5 += hzs[s5 * CL + c];
        a6 += hzs[s6 * CL + c]; a7 += hzs[s7 * CL + c];
    }
    for (; p < p1; ++p) a0 += hzs[csr[p] * CL + c];
    float sum = ((a0 + a1) + (a2 + a3)) + ((a4 + a5) + (a6 + a7));
    float v = dis[i] * sum + b2[c];
    z[i * CL + c] = v > 0.f ? v : 0.f;
}

// ---------------- Decoder layer 1: d = relu(z @ Wd1 + bd1) ----------------

__global__ void k_dmlp(const float* __restrict__ z, const float* __restrict__ Wd1,
                       const float* __restrict__ bd1, float* __restrict__ dout) {
    int g = blockIdx.x * blockDim.x + threadIdx.x;
    int n = g >> 6, c = g & 63;
    if (n >= NN) return;
    float acc = bd1[c];
    const float* zp = z + n * CL;
#pragma unroll
    for (int k = 0; k < CL; ++k) acc = fmaf(zp[k], Wd1[k * CH + c], acc);
    dout[n * CH + c] = acc > 0.f ? acc : 0.f;
}

// ---------------- Decoder layer 2 (MFMA split-bf16) + sigmoid ----------------
// v4: 64-row x 128-col tiles (3128 blocks). B-tile in 32KB LDS (staged once,
// swizzled) -> 5 blocks/CU (~62% occ) AND low-latency pipelinable B-reads.
// Combines round-6's ILP with 2.5x its residency; A direct from global.

__launch_bounds__(256)
__global__ void k_dec2(const float* __restrict__ d,
                       const unsigned short* __restrict__ wt2_hi,
                       const unsigned short* __restrict__ wt2_lo,
                       const float* __restrict__ bd2,
                       float* __restrict__ out) {
    __shared__ alignas(16) char Bh[16384], Bl[16384];  // [128 n][64 k] bf16, swizzled
    const int t = threadIdx.x;
    const int w = t >> 6, l = t & 63;
    const int mt = blockIdx.x >> 2, nt = blockIdx.x & 3;
    const int row0 = mt * 64, col0 = nt * 128;
    const int lq = l >> 4, lr = l & 15;

    // stage B tile: wt2 rows col0..col0+127 (128 B each), coalesced, swizzled
    {
        int r = t >> 1, hf = (t & 1) * 64;
        const char* sh = (const char*)wt2_hi + (col0 + r) * 128 + hf;
        const char* sl = (const char*)wt2_lo + (col0 + r) * 128 + hf;
#pragma unroll
        for (int j = 0; j < 4; ++j) {
            int so = (r * 128 + hf + j * 16) ^ ((r & 7) << 4);
            *(int4*)(Bh + so) = *(const int4*)(sh + j * 16);
            *(int4*)(Bl + so) = *(const int4*)(sl + j * 16);
        }
    }

    // A fragments direct from global: lane holds A[m=lr][k=ks*32+lq*8 .. +8]
    const int arow = row0 + w * 16 + lr;
    const bool inb = arow < NN;
    bf16x8 aH[2], aL[2];
#pragma unroll
    for (int ks = 0; ks < 2; ++ks) {
        const float* ap = d + arow * CH + ks * 32 + lq * 8;
        float4 v0 = inb ? *(const float4*)ap : make_float4(0.f, 0.f, 0.f, 0.f);
        float4 v1 = inb ? *(const float4*)(ap + 4) : make_float4(0.f, 0.f, 0.f, 0.f);
        split8(v0, v1, aH[ks], aL[ks]);
    }
    __syncthreads();

    f32x4 zero4 = {0.f, 0.f, 0.f, 0.f};
    f32x4 acc[8];
#pragma unroll
    for (int f = 0; f < 8; ++f) acc[f] = zero4;

#pragma unroll
    for (int f = 0; f < 8; ++f) {
#pragma unroll
        for (int ks = 0; ks < 2; ++ks) {
            int kb = ks * 64 + lq * 16;
            bf16x8 bH = frag(Bh, f * 16 + lr, kb);
            bf16x8 bL = frag(Bl, f * 16 + lr, kb);
            acc[f] = __builtin_amdgcn_mfma_f32_16x16x32_bf16(aH[ks], bH, acc[f], 0, 0, 0);
            acc[f] = __builtin_amdgcn_mfma_f32_16x16x32_bf16(aL[ks], bH, acc[f], 0, 0, 0);
            acc[f] = __builtin_amdgcn_mfma_f32_16x16x32_bf16(aH[ks], bL, acc[f], 0, 0, 0);
        }
    }

#pragma unroll
    for (int f = 0; f < 8; ++f) {
        int c = col0 + f * 16 + lr;
        float bias = bd2[c];
#pragma unroll
        for (int i = 0; i < 4; ++i) {
            int row = row0 + w * 16 + lq * 4 + i;
            if (row < NN) {
                float v = acc[f][i] + bias;
                out[row * CIN + c] = 1.f / (1.f + __expf(-v));
            }
        }
    }
}

// ---------------- launch ----------------

extern "C" void kernel_launch(void* const* d_in, const int* in_sizes, int n_in,
                              void* d_out, int out_size, void* d_ws, size_t ws_size,
                              hipStream_t stream) {
    const float* x   = (const float*)d_in[0];
    const int*   ei  = (const int*)d_in[1];
    const float* W1  = (const float*)d_in[2];
    const float* b1  = (const float*)d_in[3];
    const float* W2  = (const float*)d_in[4];
    const float* b2  = (const float*)d_in[5];
    const float* Wd1 = (const float*)d_in[6];
    const float* bd1 = (const float*)d_in[7];
    const float* Wd2 = (const float*)d_in[8];
    const float* bd2 = (const float*)d_in[9];
    const int* srcIdx = ei;
    const int* dstIdx = ei + NE;
    float* out = (float*)d_out;

    // workspace layout (~46 MB)
    float* fws = (float*)d_ws;
    float* hw1 = fws;                    // NN*64 (reused as 'd' after agg1)
    float* h   = hw1 + NN * CH;          // NN*64
    float* hz  = h + NN * CH;            // NN*32
    float* z   = hz + NN * CL;           // NN*32
    float* dis = z + NN * CL;            // NN
    int* cnt    = (int*)(dis + NN);      // NN
    int* rowptr = cnt + NN;              // NN+1
    int* gcur   = rowptr + NN + 1;       // NB (bucket cursors)
    int* bsum   = gcur + NB;             // 64
    int* csr    = bsum + 64;             // NE (also pair buffer)
    uintptr_t p = (uintptr_t)(csr + NE);
    p = (p + 63) & ~(uintptr_t)63;
    unsigned short* wt1_hi = (unsigned short*)p;   // 64x512
    unsigned short* wt1_lo = wt1_hi + CIN * CH;
    unsigned short* wt2_hi = wt1_lo + CIN * CH;    // 512x64
    unsigned short* wt2_lo = wt2_hi + CIN * CH;
    float* dbuf = hw1;  // alias: hw1 dead after k_agg1

    const int nb_nodes = (NN + 255) / 256;
    const int nb_edges = (NE + 255) / 256;

    k_prep<<<256, 256, 0, stream>>>(W1, Wd2, wt1_hi, wt1_lo, wt2_hi, wt2_lo);

    k_init<<<nb_nodes, 256, 0, stream>>>(cnt, gcur);
    k_deg<<<nb_edges, 256, 0, stream>>>(dstIdx, cnt);
    k_dis<<<nb_nodes, 256, 0, stream>>>(cnt, dis);
    k_scan_block<<<NSCAN, 256, 0, stream>>>(cnt, rowptr, bsum);
    k_scan_top<<<1, 1, 0, stream>>>(bsum, rowptr);
    k_scan_add<<<nb_nodes, 256, 0, stream>>>(rowptr, bsum);
    k_scatA<<<NBLKA, 256, 0, stream>>>(srcIdx, dstIdx, rowptr, gcur, (unsigned int*)csr);
    k_scatB<<<NB, 256, 0, stream>>>(rowptr, csr);

    k_gemm1_mfma<<<(NN + 63) / 64, 256, 0, stream>>>(x, wt1_hi, wt1_lo, dis, hw1);
    k_agg1<<<(NN + 3) / 4, 256, 0, stream>>>(hw1, dis, rowptr, csr, b1, h);
    k_gemm2<<<(NN * 32 + 255) / 256, 256, 0, stream>>>(h, W2, dis, hz);
    k_agg2<<<(NN / 2 + 3) / 4, 256, 0, stream>>>(hz, dis, rowptr, csr, b2, z);
    k_dmlp<<<(NN * CH + 255) / 256, 256, 0, stream>>>(z, Wd1, bd1, dbuf);
    k_dec2<<<((NN + 63) / 64) * 4, 256, 0, stream>>>(dbuf, wt2_hi, wt2_lo, bd2, out);
}

// Round 11
// 422.034 us; speedup vs baseline: 1.2682x; 1.1674x over previous
//
#include <hip/hip_runtime.h>

#define NN 50000
#define NE 1600000
#define CIN 512
#define CH 64
#define CL 32

#define BKN 256                                // nodes per bucket
#define NB ((NN + BKN - 1) / BKN)              // 196 buckets
#define CHUNK 8192                             // edges per scatA block
#define NBLKA ((NE + CHUNK - 1) / CHUNK)       // 196
#define SEGCAP 12288                           // bucket segment cap (mean 8163 + 45 sigma)

typedef float f32x4 __attribute__((ext_vector_type(4)));
typedef short bf16x8 __attribute__((ext_vector_type(8)));

// ---------------- bf16 split helpers (RTNE, pure bit ops) ----------------

__device__ inline unsigned short bf_hi(float f) {
    union { float f; unsigned u; } a; a.f = f;
    unsigned r = a.u + 0x7FFFu + ((a.u >> 16) & 1u);
    return (unsigned short)(r >> 16);
}
__device__ inline float bf_to_f(unsigned short h) {
    union { unsigned u; float f; } b; b.u = ((unsigned)h) << 16; return b.f;
}
__device__ inline void split_bf16(float f, unsigned short& hi, unsigned short& lo) {
    hi = bf_hi(f);
    lo = bf_hi(f - bf_to_f(hi));
}
__device__ inline void split4(const float4& v, ushort4& h, ushort4& l) {
    split_bf16(v.x, h.x, l.x); split_bf16(v.y, h.y, l.y);
    split_bf16(v.z, h.z, l.z); split_bf16(v.w, h.w, l.w);
}
__device__ inline void split8(const float4& v0, const float4& v1, bf16x8& h, bf16x8& l) {
    ushort4 h0, l0, h1, l1;
    split4(v0, h0, l0); split4(v1, h1, l1);
    h = (bf16x8){(short)h0.x, (short)h0.y, (short)h0.z, (short)h0.w,
                 (short)h1.x, (short)h1.y, (short)h1.z, (short)h1.w};
    l = (bf16x8){(short)l0.x, (short)l0.y, (short)l0.z, (short)l0.w,
                 (short)l1.x, (short)l1.y, (short)l1.z, (short)l1.w};
}

// XOR-swizzled LDS frag read: planes are [row][64k] bf16, row stride 128B
__device__ inline bf16x8 frag(const char* plane, int row, int koff_bytes) {
    int off = (row * 128 + koff_bytes) ^ ((row & 7) << 4);
    return *(const bf16x8*)(plane + off);
}

// ---------------- weight prep: transpose + split to bf16 hi/lo ----------------

__global__ void k_prep(const float* __restrict__ W1, const float* __restrict__ Wd2,
                       unsigned short* __restrict__ wt1_hi, unsigned short* __restrict__ wt1_lo,
                       unsigned short* __restrict__ wt2_hi, unsigned short* __restrict__ wt2_lo) {
    int id = blockIdx.x * blockDim.x + threadIdx.x;  // 0..65535
    if (id < CIN * CH) {                 // W1: [512][64] -> wt1[n=64][k=512]
        int k = id >> 6, n = id & 63;
        unsigned short h, lo; split_bf16(W1[id], h, lo);
        wt1_hi[n * CIN + k] = h; wt1_lo[n * CIN + k] = lo;
    } else {                             // Wd2: [64][512] -> wt2[n=512][k=64]
        int e = id - CIN * CH;
        int k = e >> 9, n = e & 511;
        unsigned short h, lo; split_bf16(Wd2[e], h, lo);
        wt2_hi[n * CH + k] = h; wt2_lo[n * CH + k] = lo;
    }
}

// ---------------- CSR build (atomic-free counting) ----------------

__global__ void k_init(int* gcur) {
    int i = blockIdx.x * blockDim.x + threadIdx.x;
    if (i < NB) gcur[i] = 0;
}

// phase A: bin edge pairs into fixed-capacity bucket segments.
// pair u32 = (dst<<16) | src (both < 65536).

__launch_bounds__(256)
__global__ void k_scatA(const int* __restrict__ srcIdx, const int* __restrict__ dstIdx,
                        int* __restrict__ gcur, unsigned int* __restrict__ pairbuf) {
    __shared__ unsigned int stage[CHUNK];          // 32 KB
    __shared__ unsigned char bids[CHUNK];          // 8 KB
    __shared__ int hist[256], lbase[256], runcur[256], gbase[256];
    const int t = threadIdx.x;
    const int e0 = blockIdx.x * CHUNK;
    const int tot = min(NE - e0, CHUNK);

    hist[t] = 0; runcur[t] = 0;
    __syncthreads();

    unsigned int pr[CHUNK / 256];
    unsigned char bk[CHUNK / 256];
#pragma unroll
    for (int k = 0; k < CHUNK / 256; ++k) {
        int e = e0 + k * 256 + t;
        if (e < NE) {
            int s = srcIdx[e], d = dstIdx[e];
            pr[k] = ((unsigned)d << 16) | (unsigned)s;
            bk[k] = (unsigned char)(d >> 8);
            atomicAdd(&hist[bk[k]], 1);
        }
    }
    __syncthreads();
    // exclusive scan of hist over 256 entries
    int cb = hist[t];
    lbase[t] = cb;
    __syncthreads();
    for (int off = 1; off < 256; off <<= 1) {
        int v = (t >= off) ? lbase[t - off] : 0;
        __syncthreads();
        lbase[t] += v;
        __syncthreads();
    }
    int excl = lbase[t] - cb;
    __syncthreads();
    lbase[t] = excl;
    // reserve run in fixed-capacity segment (38K global atomics total)
    if (t < NB) {
        gbase[t] = t * SEGCAP + (cb ? atomicAdd(&gcur[t], cb) : 0);
    }
    __syncthreads();
    // pass 2: place into stage bucket-sorted
#pragma unroll
    for (int k = 0; k < CHUNK / 256; ++k) {
        int e = e0 + k * 256 + t;
        if (e < NE) {
            int b = bk[k];
            int off = lbase[b] + atomicAdd(&runcur[b], 1);
            stage[off] = pr[k];
            bids[off] = (unsigned char)b;
        }
    }
    __syncthreads();
    // copy out: consecutive i within a bucket -> consecutive positions
    for (int i = t; i < tot; i += 256) {
        int b = bids[i];
        pairbuf[gbase[b] + (i - lbase[b])] = stage[i];
    }
}

// exclusive scan of 196 bucket totals -> global csr bases
__global__ void k_bscan(const int* __restrict__ gcur, int* __restrict__ bbase,
                        int* __restrict__ rowptr) {
    __shared__ int sd[256];
    int t = threadIdx.x;
    int v = (t < NB) ? gcur[t] : 0;
    sd[t] = v;
    __syncthreads();
    for (int off = 1; off < 256; off <<= 1) {
        int u = (t >= off) ? sd[t - off] : 0;
        __syncthreads();
        sd[t] += u;
        __syncthreads();
    }
    if (t < NB) bbase[t] = sd[t] - v;
    if (t == 255) rowptr[NN] = sd[255];  // == NE
}

// phase B: per bucket — LDS-atomic degree count, prefix scan, rowptr/dis,
// node-level placement, coalesced csr segment write.

__launch_bounds__(256)
__global__ void k_scatB(const int* __restrict__ gcur, const int* __restrict__ bbase,
                        const unsigned int* __restrict__ pairbuf,
                        int* __restrict__ csr, int* __restrict__ rowptr,
                        float* __restrict__ dis) {
    __shared__ int lcsr[SEGCAP];       // 48 KB
    __shared__ int cntl[BKN], excl[BKN], lcur[BKN], sd[BKN];
    const int t = threadIdx.x, b = blockIdx.x;
    const int n0 = b * BKN;
    const int m = gcur[b];
    const int base = bbase[b];
    const unsigned int* seg = pairbuf + b * SEGCAP;

    cntl[t] = 0; lcur[t] = 0;
    __syncthreads();
    for (int i = t; i < m; i += 256)
        atomicAdd(&cntl[(int)(seg[i] >> 16) - n0], 1);
    __syncthreads();
    int c = cntl[t];
    sd[t] = c;
    __syncthreads();
    for (int off = 1; off < 256; off <<= 1) {
        int u = (t >= off) ? sd[t - off] : 0;
        __syncthreads();
        sd[t] += u;
        __syncthreads();
    }
    int ex = sd[t] - c;
    excl[t] = ex;
    int node = n0 + t;
    if (node < NN) {
        rowptr[node] = base + ex;
        dis[node] = rsqrtf((float)(c + 1));  // +1 self-loop
    }
    __syncthreads();
    for (int i = t; i < m; i += 256) {
        unsigned int pr = seg[i];
        int dL = (int)(pr >> 16) - n0;
        int slot = excl[dL] + atomicAdd(&lcur[dL], 1);
        lcsr[slot] = (int)(pr & 0xFFFFu);
    }
    __syncthreads();
    for (int i = t; i < m; i += 256) csr[base + i] = lcsr[i];
}

// ---------------- GEMM1 (MFMA split-bf16): hw1s = (x @ W1) * dis[row] ----------------
// M=50000 (64/block), N=64, K=512 (chunks of 64)

__launch_bounds__(256)
__global__ void k_gemm1_mfma(const float* __restrict__ x,
                             const unsigned short* __restrict__ wt_hi,
                             const unsigned short* __restrict__ wt_lo,
                             const float* __restrict__ dis,
                             float* __restrict__ hw1) {
    __shared__ alignas(16) char Ahi[8192], Alo[8192], Bhi[8192], Blo[8192];
    const int t = threadIdx.x;
    const int w = t >> 6, l = t & 63;
    const int row0 = blockIdx.x * 64;
    const int r = t >> 2;            // staging row 0..63
    const int kq = (t & 3) * 16;     // staging k start (elems)

    f32x4 zero4 = {0.f, 0.f, 0.f, 0.f};
    f32x4 acc[4];
#pragma unroll
    for (int f = 0; f < 4; ++f) acc[f] = zero4;

    const bool inb = (row0 + r) < NN;

    for (int kc = 0; kc < CIN; kc += 64) {
        // stage A: x tile 64x64 fp32 -> hi/lo bf16 planes (swizzled)
        const float* xp = x + (row0 + r) * CIN + kc + kq;
#pragma unroll
        for (int j = 0; j < 4; ++j) {
            float4 v = inb ? *(const float4*)(xp + j * 4) : make_float4(0.f, 0.f, 0.f, 0.f);
            ushort4 h4, l4; split4(v, h4, l4);
            int so = (r * 128 + (kq + j * 4) * 2) ^ ((r & 7) << 4);
            *(ushort4*)(Ahi + so) = h4;
            *(ushort4*)(Alo + so) = l4;
        }
        // stage B: wt1 tile [n=64][k=64] bf16 hi/lo (swizzled)
        {
            const char* bh = (const char*)wt_hi;
            const char* bl = (const char*)wt_lo;
            int kb = (t & 3) * 32;   // byte offset within 128B chunk-row
#pragma unroll
            for (int j = 0; j < 2; ++j) {
                int srcoff = r * (CIN * 2) + kc * 2 + kb + j * 16;
                int so = (r * 128 + kb + j * 16) ^ ((r & 7) << 4);
                *(int4*)(Bhi + so) = *(const int4*)(bh + srcoff);
                *(int4*)(Blo + so) = *(const int4*)(bl + srcoff);
            }
        }
        __syncthreads();
#pragma unroll
        for (int ks = 0; ks < 2; ++ks) {
            int kb = ks * 64 + (l >> 4) * 16;
            bf16x8 aH = frag(Ahi, w * 16 + (l & 15), kb);
            bf16x8 aL = frag(Alo, w * 16 + (l & 15), kb);
#pragma unroll
            for (int f = 0; f < 4; ++f) {
                bf16x8 bH = frag(Bhi, f * 16 + (l & 15), kb);
                bf16x8 bL = frag(Blo, f * 16 + (l & 15), kb);
                acc[f] = __builtin_amdgcn_mfma_f32_16x16x32_bf16(aH, bH, acc[f], 0, 0, 0);
                acc[f] = __builtin_amdgcn_mfma_f32_16x16x32_bf16(aL, bH, acc[f], 0, 0, 0);
                acc[f] = __builtin_amdgcn_mfma_f32_16x16x32_bf16(aH, bL, acc[f], 0, 0, 0);
            }
        }
        __syncthreads();
    }
    // epilogue: C/D layout col=lane&15, row=(lane>>4)*4+reg; pre-scale by dis[row]
#pragma unroll
    for (int i = 0; i < 4; ++i) {
        int row = row0 + w * 16 + (l >> 4) * 4 + i;
        if (row < NN) {
            float di = dis[row];
#pragma unroll
            for (int f = 0; f < 4; ++f)
                hw1[row * CH + f * 16 + (l & 15)] = di * acc[f][i];
        }
    }
}

// ---------------- Aggregation 1: h = relu(dis[i]*sum(hw1s) + b1), H=64 ----------------

__launch_bounds__(256)
__global__ void k_agg1(const float* __restrict__ hw1s, const float* __restrict__ dis,
                       const int* __restrict__ rowptr, const int* __restrict__ csr,
                       const float* __restrict__ b1, float* __restrict__ h) {
    int i = blockIdx.x * 4 + (threadIdx.x >> 6);
    if (i >= NN) return;
    int c = threadIdx.x & 63;
    float a0 = hw1s[i * CH + c];  // self-loop term (pre-scaled): dis[i]*hw1[i]
    float a1 = 0.f, a2 = 0.f, a3 = 0.f, a4 = 0.f, a5 = 0.f, a6 = 0.f, a7 = 0.f;
    int p = rowptr[i], p1 = rowptr[i + 1];
    for (; p + 8 <= p1; p += 8) {
        int s0 = csr[p + 0], s1 = csr[p + 1], s2 = csr[p + 2], s3 = csr[p + 3];
        int s4 = csr[p + 4], s5 = csr[p + 5], s6 = csr[p + 6], s7 = csr[p + 7];
        a0 += hw1s[s0 * CH + c]; a1 += hw1s[s1 * CH + c];
        a2 += hw1s[s2 * CH + c]; a3 += hw1s[s3 * CH + c];
        a4 += hw1s[s4 * CH + c]; a5 += hw1s[s5 * CH + c];
        a6 += hw1s[s6 * CH + c]; a7 += hw1s[s7 * CH + c];
    }
    for (; p < p1; ++p) a0 += hw1s[csr[p] * CH + c];
    float sum = ((a0 + a1) + (a2 + a3)) + ((a4 + a5) + (a6 + a7));
    float v = dis[i] * sum + b1[c];
    h[i * CH + c] = v > 0.f ? v : 0.f;
}

// ---------------- GEMM2: hzs = (h @ W2) * dis[n]  (50000x64 @ 64x32) ----------------

__global__ void k_gemm2(const float* __restrict__ h, const float* __restrict__ W2,
                        const float* __restrict__ dis, float* __restrict__ hz) {
    int t = blockIdx.x * blockDim.x + threadIdx.x;
    int n = t >> 5, c = t & 31;
    if (n >= NN) return;
    float acc = 0.f;
#pragma unroll
    for (int k = 0; k < CH; k++) acc = fmaf(h[n * CH + k], W2[k * CL + c], acc);
    hz[n * CL + c] = acc * dis[n];
}

// ---------------- Aggregation 2: z = relu(dis[i]*sum(hzs) + b2), H=32 ----------------

__launch_bounds__(256)
__global__ void k_agg2(const float* __restrict__ hzs, const float* __restrict__ dis,
                       const int* __restrict__ rowptr, const int* __restrict__ csr,
                       const float* __restrict__ b2, float* __restrict__ z) {
    int wave = blockIdx.x * 4 + (threadIdx.x >> 6);
    int half = (threadIdx.x >> 5) & 1;
    int i = wave * 2 + half;
    if (i >= NN) return;
    int c = threadIdx.x & 31;
    float a0 = hzs[i * CL + c];
    float a1 = 0.f, a2 = 0.f, a3 = 0.f, a4 = 0.f, a5 = 0.f, a6 = 0.f, a7 = 0.f;
    int p = rowptr[i], p1 = rowptr[i + 1];
    for (; p + 8 <= p1; p += 8) {
        int s0 = csr[p + 0], s1 = csr[p + 1], s2 = csr[p + 2], s3 = csr[p + 3];
        int s4 = csr[p + 4], s5 = csr[p + 5], s6 = csr[p + 6], s7 = csr[p + 7];
        a0 += hzs[s0 * CL + c]; a1 += hzs[s1 * CL + c];
        a2 += hzs[s2 * CL + c]; a3 += hzs[s3 * CL + c];
        a4 += hzs[s4 * CL + c]; a5 += hzs[s5 * CL + c];
        a6 += hzs[s6 * CL + c]; a7 += hzs[s7 * CL + c];
    }
    for (; p < p1; ++p) a0 += hzs[csr[p] * CL + c];
    float sum = ((a0 + a1) + (a2 + a3)) + ((a4 + a5) + (a6 + a7));
    float v = dis[i] * sum + b2[c];
    z[i * CL + c] = v > 0.f ? v : 0.f;
}

// ---------------- Decoder layer 1: d = relu(z @ Wd1 + bd1) ----------------

__global__ void k_dmlp(const float* __restrict__ z, const float* __restrict__ Wd1,
                       const float* __restrict__ bd1, float* __restrict__ dout) {
    int g = blockIdx.x * blockDim.x + threadIdx.x;
    int n = g >> 6, c = g & 63;
    if (n >= NN) return;
    float acc = bd1[c];
    const float* zp = z + n * CL;
#pragma unroll
    for (int k = 0; k < CL; ++k) acc = fmaf(zp[k], Wd1[k * CH + c], acc);
    dout[n * CH + c] = acc > 0.f ? acc : 0.f;
}

// ---------------- Decoder layer 2 (MFMA split-bf16) + sigmoid ----------------
// v4: 64-row x 128-col tiles. B-tile in 32KB LDS (staged once, swizzled)
// -> ~5 blocks/CU AND low-latency pipelinable B-reads. A direct from global.

__launch_bounds__(256)
__global__ void k_dec2(const float* __restrict__ d,
                       const unsigned short* __restrict__ wt2_hi,
                       const unsigned short* __restrict__ wt2_lo,
                       const float* __restrict__ bd2,
                       float* __restrict__ out) {
    __shared__ alignas(16) char Bh[16384], Bl[16384];  // [128 n][64 k] bf16, swizzled
    const int t = threadIdx.x;
    const int w = t >> 6, l = t & 63;
    const int mt = blockIdx.x >> 2, nt = blockIdx.x & 3;
    const int row0 = mt * 64, col0 = nt * 128;
    const int lq = l >> 4, lr = l & 15;

    // stage B tile: wt2 rows col0..col0+127 (128 B each), coalesced, swizzled
    {
        int r = t >> 1, hf = (t & 1) * 64;
        const char* sh = (const char*)wt2_hi + (col0 + r) * 128 + hf;
        const char* sl = (const char*)wt2_lo + (col0 + r) * 128 + hf;
#pragma unroll
        for (int j = 0; j < 4; ++j) {
            int so = (r * 128 + hf + j * 16) ^ ((r & 7) << 4);
            *(int4*)(Bh + so) = *(const int4*)(sh + j * 16);
            *(int4*)(Bl + so) = *(const int4*)(sl + j * 16);
        }
    }

    // A fragments direct from global: lane holds A[m=lr][k=ks*32+lq*8 .. +8]
    const int arow = row0 + w * 16 + lr;
    const bool inb = arow < NN;
    bf16x8 aH[2], aL[2];
#pragma unroll
    for (int ks = 0; ks < 2; ++ks) {
        const float* ap = d + arow * CH + ks * 32 + lq * 8;
        float4 v0 = inb ? *(const float4*)ap : make_float4(0.f, 0.f, 0.f, 0.f);
        float4 v1 = inb ? *(const float4*)(ap + 4) : make_float4(0.f, 0.f, 0.f, 0.f);
        split8(v0, v1, aH[ks], aL[ks]);
    }
    __syncthreads();

    f32x4 zero4 = {0.f, 0.f, 0.f, 0.f};
    f32x4 acc[8];
#pragma unroll
    for (int f = 0; f < 8; ++f) acc[f] = zero4;

#pragma unroll
    for (int f = 0; f < 8; ++f) {
#pragma unroll
        for (int ks = 0; ks < 2; ++ks) {
            int kb = ks * 64 + lq * 16;
            bf16x8 bH = frag(Bh, f * 16 + lr, kb);
            bf16x8 bL = frag(Bl, f * 16 + lr, kb);
            acc[f] = __builtin_amdgcn_mfma_f32_16x16x32_bf16(aH[ks], bH, acc[f], 0, 0, 0);
            acc[f] = __builtin_amdgcn_mfma_f32_16x16x32_bf16(aL[ks], bH, acc[f], 0, 0, 0);
            acc[f] = __builtin_amdgcn_mfma_f32_16x16x32_bf16(aH[ks], bL, acc[f], 0, 0, 0);
        }
    }

#pragma unroll
    for (int f = 0; f < 8; ++f) {
        int c = col0 + f * 16 + lr;
        float bias = bd2[c];
#pragma unroll
        for (int i = 0; i < 4; ++i) {
            int row = row0 + w * 16 + lq * 4 + i;
            if (row < NN) {
                float v = acc[f][i] + bias;
                out[row * CIN + c] = 1.f / (1.f + __expf(-v));
            }
        }
    }
}

// ---------------- launch ----------------

extern "C" void kernel_launch(void* const* d_in, const int* in_sizes, int n_in,
                              void* d_out, int out_size, void* d_ws, size_t ws_size,
                              hipStream_t stream) {
    const float* x   = (const float*)d_in[0];
    const int*   ei  = (const int*)d_in[1];
    const float* W1  = (const float*)d_in[2];
    const float* b1  = (const float*)d_in[3];
    const float* W2  = (const float*)d_in[4];
    const float* b2  = (const float*)d_in[5];
    const float* Wd1 = (const float*)d_in[6];
    const float* bd1 = (const float*)d_in[7];
    const float* Wd2 = (const float*)d_in[8];
    const float* bd2 = (const float*)d_in[9];
    const int* srcIdx = ei;
    const int* dstIdx = ei + NE;
    float* out = (float*)d_out;

    // workspace layout (~46 MB)
    float* fws = (float*)d_ws;
    float* hw1 = fws;                    // NN*64 (reused as 'd' after agg1)
    float* h   = hw1 + NN * CH;          // NN*64 (pairbuf aliases this early)
    float* hz  = h + NN * CH;            // NN*32
    float* z   = hz + NN * CL;           // NN*32
    float* dis = z + NN * CL;            // NN
    int* gcur   = (int*)(dis + NN);      // NB (bucket counts)
    int* bbase  = gcur + NB;             // NB
    int* rowptr = bbase + NB;            // NN+1
    int* csr    = rowptr + NN + 1;       // NE
    uintptr_t p = (uintptr_t)(csr + NE);
    p = (p + 63) & ~(uintptr_t)63;
    unsigned short* wt1_hi = (unsigned short*)p;   // 64x512
    unsigned short* wt1_lo = wt1_hi + CIN * CH;
    unsigned short* wt2_hi = wt1_lo + CIN * CH;    // 512x64
    unsigned short* wt2_lo = wt2_hi + CIN * CH;
    unsigned int* pairbuf = (unsigned int*)h;  // NB*SEGCAP u32 = 9.6MB <= 12.8MB (h)
    float* dbuf = hw1;  // alias: hw1 dead after k_agg1

    k_prep<<<256, 256, 0, stream>>>(W1, Wd2, wt1_hi, wt1_lo, wt2_hi, wt2_lo);

    k_init<<<1, 256, 0, stream>>>(gcur);
    k_scatA<<<NBLKA, 256, 0, stream>>>(srcIdx, dstIdx, gcur, pairbuf);
    k_bscan<<<1, 256, 0, stream>>>(gcur, bbase, rowptr);
    k_scatB<<<NB, 256, 0, stream>>>(gcur, bbase, pairbuf, csr, rowptr, dis);

    k_gemm1_mfma<<<(NN + 63) / 64, 256, 0, stream>>>(x, wt1_hi, wt1_lo, dis, hw1);
    k_agg1<<<(NN + 3) / 4, 256, 0, stream>>>(hw1, dis, rowptr, csr, b1, h);
    k_gemm2<<<(NN * 32 + 255) / 256, 256, 0, stream>>>(h, W2, dis, hz);
    k_agg2<<<(NN / 2 + 3) / 4, 256, 0, stream>>>(hz, dis, rowptr, csr, b2, z);
    k_dmlp<<<(NN * CH + 255) / 256, 256, 0, stream>>>(z, Wd1, bd1, dbuf);
    k_dec2<<<((NN + 63) / 64) * 4, 256, 0, stream>>>(dbuf, wt2_hi, wt2_lo, bd2, out);
}